// Round 1
// baseline (628.865 us; speedup 1.0000x reference)
//
#include <hip/hip_runtime.h>

// ---------------------------------------------------------------------------
// Round 11: encoder occupancy experiment.
//  Encoder: 128 blocks x 1024 thr. 16 waves = 4 layers x 4 quarter-col-slices
//    (16 cols each). 4 waves/SIMD (vs 2): hides correlated dependency-chain
//    stalls (post-barrier ds_read, 2-deep MFMA chains, 8-trans ew chains).
//    Weights shrink to 16 frags = 64 VGPR/wave -> fits the 128-reg cap.
//  Decoder: UNCHANGED from round 10 (attribution anchor), 296 us measured.
// ---------------------------------------------------------------------------

#define S_LEN 120
#define BATCH 2048
#define NIN   6
#define H     64
#define NL    4
#define TLEN  120

#define HPAD 72            // row stride in halves (144 B)

#define FRAGS_HALF 60      // col-sliced: 12 (layer0) + 3*16
#define PACK_H8    (2 * FRAGS_HALF * 4 * 64)
#define PROJ_H8    (2 * 64)
#define NPACK      ((PACK_H8 + PROJ_H8) * 8)   // 246784 fp16 elements
#define EPACK_EL   (256 * 64 * 8)              // encoder pipeline pack
#define NTOT       (NPACK + EPACK_EL)          // 377856 (~756 KB)

// workspace byte offsets (after the weight pack)
#define WS_HOFF (768 * 1024)                   // h: 4*2048*64 fp16 = 1 MB
#define WS_COFF (WS_HOFF + 1024 * 1024)        // c: 4*2048*64 f32 = 2 MB

#define PERM(kk) ((((kk) & 3) << 4) | ((kk) >> 2))   // pi^-1
#define PI(c)    ((((c) & 15) << 2) | ((c) >> 4))    // pi

typedef _Float16 h8    __attribute__((ext_vector_type(8)));
typedef _Float16 hh2   __attribute__((ext_vector_type(2)));
typedef float    f32x4 __attribute__((ext_vector_type(4)));

__device__ __forceinline__ void bar_lgkm() {
  asm volatile("s_waitcnt lgkmcnt(0)\n\ts_barrier" ::: "memory");
}

// ---------------------------------------------------------------------------
// Weight pack (identical to rounds 5-10).
// ---------------------------------------------------------------------------
__global__ void prep_weights(const float* __restrict__ eWih0,
                             const float* __restrict__ eWih,
                             const float* __restrict__ eWhh,
                             const float* __restrict__ dWih0,
                             const float* __restrict__ dWih,
                             const float* __restrict__ dWhh,
                             const float* __restrict__ linW,
                             _Float16* __restrict__ wq) {
  int idx = blockIdx.x * blockDim.x + threadIdx.x;
  if (idx >= NTOT) return;

  if (idx >= NPACK) {                      // ---- encoder pipeline pack ----
    int p    = idx - NPACK;
    int j    = p & 7;
    int lane = (p >> 3) & 63;
    int fe   = p >> 9;
    int kt   = fe & 3, nt = (fe >> 2) & 15, l = fe >> 6;
    int g    = nt * 16 + (lane & 15);
    int koff = ((lane >> 4) << 3) + j;
    float v = 0.0f;
    if (l == 0) {
      if (kt == 0)      v = (koff < NIN) ? eWih0[g * NIN + koff] : 0.0f;
      else if (kt == 1) v = 0.0f;
      else { int kk = (kt - 2) * 32 + koff; v = eWhh[g * H + PERM(kk)]; }
    } else {
      if (kt < 2) { int kk = kt * 32 + koff;
                    v = eWih[((l - 1) * 256 + g) * H + PERM(kk)]; }
      else        { int kk = (kt - 2) * 32 + koff;
                    v = eWhh[(l * 256 + g) * H + PERM(kk)]; }
    }
    wq[idx] = (_Float16)v;
    return;
  }

  if (idx >= PACK_H8 * 8) {                // ---- linW A-layout frags ----
    int p    = idx - PACK_H8 * 8;
    int j    = p & 7;
    int lane = (p >> 3) & 63;
    int fr   = p >> 9;
    int m    = lane & 15;
    int k    = fr * 32 + ((lane >> 4) << 3) + j;
    wq[idx] = (_Float16)((m < NIN) ? linW[m * H + k] : 0.0f);
    return;
  }

  // ---- col-sliced pack (decoder uses dec half) ----
  const int j    = idx & 7;
  const int lane = (idx >> 3) & 63;
  const int wv   = (idx >> 9) & 3;
  const int fh   = idx >> 11;
  const int f    = fh % FRAGS_HALF;
  const int half = fh / FRAGS_HALF;
  const float* Wi0 = half ? dWih0 : eWih0;
  const float* Wi  = half ? dWih  : eWih;
  const float* Wh  = half ? dWhh  : eWhh;
  int l, q, kt;
  if (f < 12) { l = 0; q = f / 3; kt = f % 3; }
  else        { int ff = f - 12; l = 1 + ff / 16; ff %= 16; q = ff / 4; kt = ff % 4; }
  const int g    = q * 64 + wv * 16 + (lane & 15);
  const int k_in = ((lane >> 4) << 3) + j;
  float v;
  if (l == 0) {
    if (kt == 0) v = (k_in < NIN) ? Wi0[g * NIN + k_in] : 0.0f;
    else         v = Wh[g * H + (kt - 1) * 32 + k_in];
  } else {
    if (kt < 2) v = Wi[((l - 1) * 256 + g) * H + kt * 32 + k_in];
    else        v = Wh[(l * 256 + g) * H + (kt - 2) * 32 + k_in];
  }
  wq[idx] = (_Float16)v;
}

// ---------------------------------------------------------------------------
__device__ __forceinline__ float rcpf(float x) { return __builtin_amdgcn_rcpf(x); }
__device__ __forceinline__ f32x4 mf(h8 a, h8 b, f32x4 c) {
  return __builtin_amdgcn_mfma_f32_16x16x32_f16(a, b, c, 0, 0, 0);
}
#define SPLAT(v) ((f32x4){(v), (v), (v), (v)})

// merged-rcp LSTM cell: 5 exp + 3 rcp (+2 clamps); absmax-validated R6-R10.
__device__ __forceinline__ float ew_one(float gi, float gf, float gg, float go,
                                        float& c) {
  gg = fminf(fmaxf(gg, -20.0f), 20.0f);
  float eni = __expf(-gi);
  float e2g = __expf(2.0f * gg);
  float enf = __expf(-gf);
  float eno = __expf(-go);
  c = c * rcpf(1.0f + enf) + (e2g - 1.0f) * rcpf((1.0f + eni) * (e2g + 1.0f));
  float cc = fminf(fmaxf(c, -20.0f), 20.0f);
  float e2c = __expf(2.0f * cc);
  return (e2c - 1.0f) * rcpf((1.0f + eno) * (e2c + 1.0f));
}

__device__ __forceinline__ void cell_ew(f32x4 g0, f32x4 g1, f32x4 g2, f32x4 g3,
                                        f32x4& c, _Float16* outbuf,
                                        int quad, int r16, int lw) {
  #pragma unroll
  for (int r = 0; r < 4; r++) {
    float cv = c[r];
    float hv = ew_one(g0[r], g1[r], g2[r], g3[r], cv);
    c[r] = cv;
    outbuf[(quad * 4 + r) * HPAD + lw * 16 + r16] = (_Float16)hv;
  }
}
__device__ __forceinline__ void fireH(const h8 (&w)[16], h8 ai0, h8 ai1,
                                      const f32x4 (&ac)[4], f32x4& c,
                                      _Float16* outbuf, int quad, int r16, int lw) {
  f32x4 g0 = mf(ai1, w[1],  mf(ai0, w[0],  ac[0]));
  f32x4 g1 = mf(ai1, w[5],  mf(ai0, w[4],  ac[1]));
  f32x4 g2 = mf(ai1, w[9],  mf(ai0, w[8],  ac[2]));
  f32x4 g3 = mf(ai1, w[13], mf(ai0, w[12], ac[3]));
  cell_ew(g0, g1, g2, g3, c, outbuf, quad, r16, lw);
}
__device__ __forceinline__ void precH(const h8 (&w)[16], h8 ar0, h8 ar1,
                                      f32x4 b, f32x4 (&ac)[4]) {
  ac[0] = mf(ar1, w[3],  mf(ar0, w[2],  SPLAT(b[0])));
  ac[1] = mf(ar1, w[7],  mf(ar0, w[6],  SPLAT(b[1])));
  ac[2] = mf(ar1, w[11], mf(ar0, w[10], SPLAT(b[2])));
  ac[3] = mf(ar1, w[15], mf(ar0, w[14], SPLAT(b[3])));
}
__device__ __forceinline__ void fire0(const h8 (&w)[12], h8 ax,
                                      const f32x4 (&ac)[4], f32x4& c,
                                      _Float16* outbuf, int quad, int r16, int lw) {
  f32x4 g0 = mf(ax, w[0], ac[0]);
  f32x4 g1 = mf(ax, w[3], ac[1]);
  f32x4 g2 = mf(ax, w[6], ac[2]);
  f32x4 g3 = mf(ax, w[9], ac[3]);
  cell_ew(g0, g1, g2, g3, c, outbuf, quad, r16, lw);
}
__device__ __forceinline__ void prec0(const h8 (&w)[12], h8 ar0, h8 ar1,
                                      f32x4 b, f32x4 (&ac)[4]) {
  ac[0] = mf(ar1, w[2],  mf(ar0, w[1],  SPLAT(b[0])));
  ac[1] = mf(ar1, w[5],  mf(ar0, w[4],  SPLAT(b[1])));
  ac[2] = mf(ar1, w[8],  mf(ar0, w[7],  SPLAT(b[2])));
  ac[3] = mf(ar1, w[11], mf(ar0, w[10], SPLAT(b[3])));
}
__device__ __forceinline__ void readA(const _Float16* buf, int r16, int quad,
                                      h8& a0, h8& a1) {
  a0 = *(const h8*)(buf + r16 * HPAD + quad * 8);
  a1 = *(const h8*)(buf + r16 * HPAD + 32 + quad * 8);
}

// ===========================================================================
// ENCODER kernel: 128 blocks x 1024 threads.
// 16 waves = 4 layers x 4 quarter-col-slices (16 cols each) -> 4 waves/SIMD.
// Per wave: 4 n-tiles (one per gate quadrant) x 4 k-frags = 16 MFMA,
// 4 ew_one/thread. Weights: 16 frags = 64 VGPR (fits 128-reg cap).
// LDS layout / pack / PERM conventions identical to round 10.
// ===========================================================================
__global__ void __launch_bounds__(1024, 4)
lstm_enc(const float* __restrict__ X,
         const float* __restrict__ encb,
         const h8* __restrict__ WQ,
         _Float16* __restrict__ hG,
         float* __restrict__ cG) {
  __shared__ _Float16 Hb[NL][2][16][HPAD];   // 18432 B
  __shared__ _Float16 Xb[2][16][HPAD];       //  4608 B

  const int tid  = threadIdx.x;
  const int wv   = tid >> 6;        // 0..15
  const int lane = tid & 63;
  const int quad = lane >> 4;
  const int r16  = lane & 15;
  const int sl   = wv >> 2;         // quarter-col-slice 0..3
  const int lw   = wv & 3;          // layer
  const int bbase = blockIdx.x * 16;

  {
    float* p = (float*)&Hb[0][0][0][0];
    for (int i = tid; i < 4608; i += 1024) p[i] = 0.0f;
    float* px = (float*)&Xb[0][0][0];
    for (int i = tid; i < 1152; i += 1024) px[i] = 0.0f;
  }
  if (tid < 16 * NIN) {
    int m = tid / NIN, ii = tid - m * NIN;
    Xb[0][m][ii] = (_Float16)X[((size_t)0 * BATCH + bbase + m) * NIN + ii];
  }

  // weights: 4 n-tiles {q*4 + sl}, 4 k-tiles each (16 frags = 64 VGPR)
  h8 we[4][4];
  #pragma unroll
  for (int q = 0; q < 4; q++)
    #pragma unroll
    for (int kt = 0; kt < 4; kt++)
      we[q][kt] =
          WQ[(PACK_H8 + PROJ_H8) +
             ((lw * 64 + (q * 4 + sl) * 4 + kt) * 64 + lane)];
  f32x4 ben;
  #pragma unroll
  for (int q = 0; q < 4; q++)
    ben[q] = encb[lw * 256 + q * 64 + sl * 16 + r16];

  f32x4 ce = SPLAT(0.f);

  // 2-deep x prefetch: wave (lw=0, sl=0), lanes 0..47, 2 floats each
  const bool pfLane = (wv == 0) && (lane < 48);
  float pf0 = 0.f, pf1 = 0.f;
  if (pfLane) {
    const float* xs = X + ((size_t)1 * BATCH + bbase) * NIN;
    pf0 = xs[lane * 2]; pf1 = xs[lane * 2 + 1];
  }

  __syncthreads();

  #pragma unroll 1
  for (int i = 0; i < S_LEN + NL - 1; i++) {     // 123 intervals
    const int p = i & 1;
    const bool active = (i >= lw) && (i - lw < S_LEN);
    if (active) {
      const _Float16* inb = (lw == 0) ? &Xb[p][0][0] : &Hb[lw - 1][p ^ 1][0][0];
      const _Float16* rcb = &Hb[lw][p ^ 1][0][0];
      h8 ai0 = *(const h8*)(inb + r16 * HPAD + quad * 8);
      h8 ai1 = {};
      if (lw) ai1 = *(const h8*)(inb + r16 * HPAD + 32 + quad * 8);
      h8 ar0 = *(const h8*)(rcb + r16 * HPAD + quad * 8);
      h8 ar1 = *(const h8*)(rcb + r16 * HPAD + 32 + quad * 8);

      float nf0 = 0.f, nf1 = 0.f;
      if (pfLane && (i + 2 < S_LEN)) {
        const float* xs = X + ((size_t)(i + 2) * BATCH + bbase) * NIN;
        nf0 = xs[lane * 2]; nf1 = xs[lane * 2 + 1];
      }

      f32x4 a[4];
      #pragma unroll
      for (int q = 0; q < 4; q++) {
        f32x4 t = SPLAT(ben[q]);
        t = mf(ai0, we[q][0], t);
        if (lw) t = mf(ai1, we[q][1], t);
        t = mf(ar0, we[q][2], t);
        t = mf(ar1, we[q][3], t);
        a[q] = t;
      }

      _Float16* wb = &Hb[lw][p][0][0];
      #pragma unroll
      for (int r = 0; r < 4; r++) {
        float cv = ce[r];
        float hv = ew_one(a[0][r], a[1][r], a[2][r], a[3][r], cv);
        ce[r] = cv;
        // permuted layout: col c = sl*16+r16 lands at 4*r16+sl
        wb[(quad * 4 + r) * HPAD + 4 * r16 + sl] = (_Float16)hv;
      }

      if (pfLane && (i + 1 < S_LEN)) {
        const int pe0 = lane * 2, pe1 = pe0 + 1;
        Xb[p ^ 1][pe0 / NIN][pe0 % NIN] = (_Float16)pf0;
        Xb[p ^ 1][pe1 / NIN][pe1 % NIN] = (_Float16)pf1;
      }
      pf0 = nf0; pf1 = nf1;
    }
    bar_lgkm();
  }

  // ---- store c to global (per-lane direct) ----
  #pragma unroll
  for (int r = 0; r < 4; r++)
    cG[((size_t)lw * BATCH + bbase + quad * 4 + r) * H + sl * 16 + r16] = ce[r];

  // ---- store final h (unpermute via PI) to global ----
  #pragma unroll
  for (int u = 0; u < 4; u++) {
    int i2 = tid + u * 1024;
    int c = i2 & 63, m = (i2 >> 6) & 15, l = (i2 >> 10) & 3;
    hG[((size_t)l * BATCH + bbase + m) * H + c] =
        Hb[l][(l + 1) & 1][m][PI(c)];
  }
}

// ===========================================================================
// DECODER kernel: UNCHANGED from round 10. 128 blocks x 256 threads
// (1 wave/SIMD, full VGPR budget), col-sliced, bar_lgkm sync.
// ===========================================================================
__global__ void __launch_bounds__(256, 1)
lstm_dec(const float* __restrict__ X,
         const float* __restrict__ decb,
         const float* __restrict__ linb,
         const h8* __restrict__ WQ,
         const _Float16* __restrict__ hG,
         const float* __restrict__ cG,
         float* __restrict__ out) {
  __shared__ _Float16 Hb[NL][2][16][HPAD];   // 18432 B

  const int tid   = threadIdx.x;
  const int lw    = tid >> 6;
  const int lane  = tid & 63;
  const int quad  = lane >> 4;
  const int r16   = lane & 15;
  const int bbase = blockIdx.x * 16;

  // load encoder-final h into Hb[l][1]
  #pragma unroll
  for (int u = 0; u < 16; u++) {
    int i2 = tid + u * 256;
    int l = i2 >> 10, m = (i2 >> 6) & 15, c = i2 & 63;
    Hb[l][1][m][c] = hG[((size_t)l * BATCH + bbase + m) * H + c];
  }

  // c slices
  f32x4 cs0, cs1, cs2, cs3;
  #pragma unroll
  for (int r = 0; r < 4; r++) {
    cs0[r] = cG[((size_t)0 * BATCH + bbase + quad * 4 + r) * H + lw * 16 + r16];
    cs1[r] = cG[((size_t)1 * BATCH + bbase + quad * 4 + r) * H + lw * 16 + r16];
    cs2[r] = cG[((size_t)2 * BATCH + bbase + quad * 4 + r) * H + lw * 16 + r16];
    cs3[r] = cG[((size_t)3 * BATCH + bbase + quad * 4 + r) * H + lw * 16 + r16];
  }

  // weights + biases
  h8 w0[12], w1[16], w2[16], w3[16];
  #pragma unroll
  for (int f = 0; f < 12; f++) w0[f] = WQ[((FRAGS_HALF + f)      * 4 + lw) * 64 + lane];
  #pragma unroll
  for (int f = 0; f < 16; f++) w1[f] = WQ[((FRAGS_HALF + 12 + f) * 4 + lw) * 64 + lane];
  #pragma unroll
  for (int f = 0; f < 16; f++) w2[f] = WQ[((FRAGS_HALF + 28 + f) * 4 + lw) * 64 + lane];
  #pragma unroll
  for (int f = 0; f < 16; f++) w3[f] = WQ[((FRAGS_HALF + 44 + f) * 4 + lw) * 64 + lane];

  f32x4 b0, b1, b2, b3;
  #pragma unroll
  for (int q = 0; q < 4; q++) {
    b0[q] = decb[0 * 256 + q * 64 + lw * 16 + r16];
    b1[q] = decb[1 * 256 + q * 64 + lw * 16 + r16];
    b2[q] = decb[2 * 256 + q * 64 + lw * 16 + r16];
    b3[q] = decb[3 * 256 + q * 64 + lw * 16 + r16];
  }

  h8 lwA0 = WQ[PACK_H8 + lane];
  h8 lwA1 = WQ[PACK_H8 + 64 + lane];
  f32x4 lbq;
  #pragma unroll
  for (int r = 0; r < 4; r++)
    lbq[r] = (quad * 4 + r < NIN) ? linb[quad * 4 + r] : 0.0f;

  // x[119] A-frag (k = quad*8+j; only k<6 real)
  h8 xseed = {};
  if (quad == 0) {
    const float* xs = X + ((size_t)(S_LEN - 1) * BATCH + bbase + r16) * NIN;
    #pragma unroll
    for (int j = 0; j < 6; j++) xseed[j] = (_Float16)xs[j];
  }

  __syncthreads();   // h-load visible

  // seed accumulators from encoder-final h
  f32x4 ac0[4], ac1[4], ac2[4], ac3[4];
  {
    h8 s0, s1;
    readA(&Hb[0][1][0][0], r16, quad, s0, s1); prec0(w0, s0, s1, b0, ac0);
    readA(&Hb[1][1][0][0], r16, quad, s0, s1); precH(w1, s0, s1, b1, ac1);
    readA(&Hb[2][1][0][0], r16, quad, s0, s1); precH(w2, s0, s1, b2, ac2);
  }

  #pragma unroll 1
  for (int t = 0; t < TLEN; t++) {
    const int cur = t & 1, prv = cur ^ 1;
    // ---- interval A: proj(h3[t-1]) + layer-0 fire + acc3 precompute ----
    {
      h8 ar0, ar1;
      readA(&Hb[3][prv][0][0], r16, quad, ar0, ar1);
      h8 ax;
      if (t == 0) {
        ax = xseed;
      } else {
        f32x4 ap = lbq;
        ap = mf(lwA0, ar0, ap);     // A = linW (m=feature), B = h3 (n=batch)
        ap = mf(lwA1, ar1, ap);
        if (lw == 0) {
          #pragma unroll
          for (int r = 0; r < 4; r++) {
            const int fm = quad * 4 + r;
            if (fm < NIN)
              out[((size_t)(t - 1) * BATCH + bbase + r16) * NIN + fm] = ap[r];
          }
        }
        float x0 = __shfl(ap[0], r16);
        float x1 = __shfl(ap[1], r16);
        float x2 = __shfl(ap[2], r16);
        float x3 = __shfl(ap[3], r16);
        float x4 = __shfl(ap[0], 16 + r16);
        float x5 = __shfl(ap[1], 16 + r16);
        h8 xa = {};
        xa[0] = (_Float16)x0; xa[1] = (_Float16)x1; xa[2] = (_Float16)x2;
        xa[3] = (_Float16)x3; xa[4] = (_Float16)x4; xa[5] = (_Float16)x5;
        h8 zz = {};
        ax = (quad == 0) ? xa : zz;
      }
      precH(w3, ar0, ar1, b3, ac3);
      fire0(w0, ax, ac0, cs0, &Hb[0][cur][0][0], quad, r16, lw);
      bar_lgkm();
    }
    // ---- interval B ----
    {
      h8 ai0, ai1;
      readA(&Hb[0][cur][0][0], r16, quad, ai0, ai1);
      fireH(w1, ai0, ai1, ac1, cs1, &Hb[1][cur][0][0], quad, r16, lw);
      prec0(w0, ai0, ai1, b0, ac0);
      bar_lgkm();
    }
    // ---- interval C ----
    {
      h8 ai0, ai1;
      readA(&Hb[1][cur][0][0], r16, quad, ai0, ai1);
      fireH(w2, ai0, ai1, ac2, cs2, &Hb[2][cur][0][0], quad, r16, lw);
      precH(w1, ai0, ai1, b1, ac1);
      bar_lgkm();
    }
    // ---- interval D ----
    {
      h8 ai0, ai1;
      readA(&Hb[2][cur][0][0], r16, quad, ai0, ai1);
      fireH(w3, ai0, ai1, ac3, cs3, &Hb[3][cur][0][0], quad, r16, lw);
      precH(w2, ai0, ai1, b2, ac2);
      bar_lgkm();
    }
  }

  // epilogue: out[TLEN-1] from h3 of last step (parity 1)
  if (lw == 0) {
    h8 ar0, ar1;
    readA(&Hb[3][1][0][0], r16, quad, ar0, ar1);
    f32x4 ap = lbq;
    ap = mf(lwA0, ar0, ap);
    ap = mf(lwA1, ar1, ap);
    #pragma unroll
    for (int r = 0; r < 4; r++) {
      const int fm = quad * 4 + r;
      if (fm < NIN)
        out[((size_t)(TLEN - 1) * BATCH + bbase + r16) * NIN + fm] = ap[r];
    }
  }
}

// ---------------------------------------------------------------------------
extern "C" void kernel_launch(void* const* d_in, const int* in_sizes, int n_in,
                              void* d_out, int out_size, void* d_ws, size_t ws_size,
                              hipStream_t stream) {
  const float* X     = (const float*)d_in[0];
  const float* eWih0 = (const float*)d_in[1];
  const float* eWih  = (const float*)d_in[2];
  const float* eWhh  = (const float*)d_in[3];
  const float* eb    = (const float*)d_in[4];
  const float* dWih0 = (const float*)d_in[5];
  const float* dWih  = (const float*)d_in[6];
  const float* dWhh  = (const float*)d_in[7];
  const float* db    = (const float*)d_in[8];
  const float* lW    = (const float*)d_in[9];
  const float* lb    = (const float*)d_in[10];

  _Float16* wq = (_Float16*)d_ws;
  _Float16* hG = (_Float16*)((char*)d_ws + WS_HOFF);
  float*    cG = (float*)((char*)d_ws + WS_COFF);

  prep_weights<<<(NTOT + 255) / 256, 256, 0, stream>>>(
      eWih0, eWih, eWhh, dWih0, dWih, dWhh, lW, wq);

  lstm_enc<<<BATCH / 16, 1024, 0, stream>>>(
      X, eb, (const h8*)wq, hG, cG);

  lstm_dec<<<BATCH / 16, 256, 0, stream>>>(
      X, db, lb, (const h8*)wq, hG, cG, (float*)d_out);
}

// Round 2
// 604.661 us; speedup vs baseline: 1.0400x; 1.0400x over previous
//
#include <hip/hip_runtime.h>

// ---------------------------------------------------------------------------
// Round 12: encoder reverted to R10 (R11's 16-wave slice regressed: duplicated
//   A-operand ds_reads per SIMD). Decoder: fire/prec wave-role split.
//   Decoder: 128 blocks x 512 thr, 8 waves = 4 col-slices x {F,P} roles,
//   2 waves/SIMD (VGPR cap 256). P computes recurrent precompute -> 64KB LDS
//   AC buffer -> F does gate MFMA + ew + h-write. FMA order bit-identical to
//   R10 (absmax canary: expect exactly 4.88e-4).
// ---------------------------------------------------------------------------

#define S_LEN 120
#define BATCH 2048
#define NIN   6
#define H     64
#define NL    4
#define TLEN  120

#define HPAD 72            // row stride in halves (144 B)

#define FRAGS_HALF 60      // col-sliced: 12 (layer0) + 3*16
#define PACK_H8    (2 * FRAGS_HALF * 4 * 64)
#define PROJ_H8    (2 * 64)
#define NPACK      ((PACK_H8 + PROJ_H8) * 8)   // 246784 fp16 elements
#define EPACK_EL   (256 * 64 * 8)              // encoder pipeline pack
#define NTOT       (NPACK + EPACK_EL)          // 377856 (~756 KB)

// workspace byte offsets (after the weight pack)
#define WS_HOFF (768 * 1024)                   // h: 4*2048*64 fp16 = 1 MB
#define WS_COFF (WS_HOFF + 1024 * 1024)        // c: 4*2048*64 f32 = 2 MB

#define PERM(kk) ((((kk) & 3) << 4) | ((kk) >> 2))   // pi^-1
#define PI(c)    ((((c) & 15) << 2) | ((c) >> 4))    // pi

typedef _Float16 h8    __attribute__((ext_vector_type(8)));
typedef _Float16 hh2   __attribute__((ext_vector_type(2)));
typedef float    f32x4 __attribute__((ext_vector_type(4)));

__device__ __forceinline__ void bar_lgkm() {
  asm volatile("s_waitcnt lgkmcnt(0)\n\ts_barrier" ::: "memory");
}

// ---------------------------------------------------------------------------
// Weight pack (identical to rounds 5-11).
// ---------------------------------------------------------------------------
__global__ void prep_weights(const float* __restrict__ eWih0,
                             const float* __restrict__ eWih,
                             const float* __restrict__ eWhh,
                             const float* __restrict__ dWih0,
                             const float* __restrict__ dWih,
                             const float* __restrict__ dWhh,
                             const float* __restrict__ linW,
                             _Float16* __restrict__ wq) {
  int idx = blockIdx.x * blockDim.x + threadIdx.x;
  if (idx >= NTOT) return;

  if (idx >= NPACK) {                      // ---- encoder pipeline pack ----
    int p    = idx - NPACK;
    int j    = p & 7;
    int lane = (p >> 3) & 63;
    int fe   = p >> 9;
    int kt   = fe & 3, nt = (fe >> 2) & 15, l = fe >> 6;
    int g    = nt * 16 + (lane & 15);
    int koff = ((lane >> 4) << 3) + j;
    float v = 0.0f;
    if (l == 0) {
      if (kt == 0)      v = (koff < NIN) ? eWih0[g * NIN + koff] : 0.0f;
      else if (kt == 1) v = 0.0f;
      else { int kk = (kt - 2) * 32 + koff; v = eWhh[g * H + PERM(kk)]; }
    } else {
      if (kt < 2) { int kk = kt * 32 + koff;
                    v = eWih[((l - 1) * 256 + g) * H + PERM(kk)]; }
      else        { int kk = (kt - 2) * 32 + koff;
                    v = eWhh[(l * 256 + g) * H + PERM(kk)]; }
    }
    wq[idx] = (_Float16)v;
    return;
  }

  if (idx >= PACK_H8 * 8) {                // ---- linW A-layout frags ----
    int p    = idx - PACK_H8 * 8;
    int j    = p & 7;
    int lane = (p >> 3) & 63;
    int fr   = p >> 9;
    int m    = lane & 15;
    int k    = fr * 32 + ((lane >> 4) << 3) + j;
    wq[idx] = (_Float16)((m < NIN) ? linW[m * H + k] : 0.0f);
    return;
  }

  // ---- col-sliced pack (decoder uses dec half) ----
  const int j    = idx & 7;
  const int lane = (idx >> 3) & 63;
  const int wv   = (idx >> 9) & 3;
  const int fh   = idx >> 11;
  const int f    = fh % FRAGS_HALF;
  const int half = fh / FRAGS_HALF;
  const float* Wi0 = half ? dWih0 : eWih0;
  const float* Wi  = half ? dWih  : eWih;
  const float* Wh  = half ? dWhh  : eWhh;
  int l, q, kt;
  if (f < 12) { l = 0; q = f / 3; kt = f % 3; }
  else        { int ff = f - 12; l = 1 + ff / 16; ff %= 16; q = ff / 4; kt = ff % 4; }
  const int g    = q * 64 + wv * 16 + (lane & 15);
  const int k_in = ((lane >> 4) << 3) + j;
  float v;
  if (l == 0) {
    if (kt == 0) v = (k_in < NIN) ? Wi0[g * NIN + k_in] : 0.0f;
    else         v = Wh[g * H + (kt - 1) * 32 + k_in];
  } else {
    if (kt < 2) v = Wi[((l - 1) * 256 + g) * H + kt * 32 + k_in];
    else        v = Wh[(l * 256 + g) * H + (kt - 2) * 32 + k_in];
  }
  wq[idx] = (_Float16)v;
}

// ---------------------------------------------------------------------------
__device__ __forceinline__ float rcpf(float x) { return __builtin_amdgcn_rcpf(x); }
__device__ __forceinline__ f32x4 mf(h8 a, h8 b, f32x4 c) {
  return __builtin_amdgcn_mfma_f32_16x16x32_f16(a, b, c, 0, 0, 0);
}
#define SPLAT(v) ((f32x4){(v), (v), (v), (v)})

// merged-rcp LSTM cell: 5 exp + 3 rcp (+2 clamps); absmax-validated R6-R11.
__device__ __forceinline__ float ew_one(float gi, float gf, float gg, float go,
                                        float& c) {
  gg = fminf(fmaxf(gg, -20.0f), 20.0f);
  float eni = __expf(-gi);
  float e2g = __expf(2.0f * gg);
  float enf = __expf(-gf);
  float eno = __expf(-go);
  c = c * rcpf(1.0f + enf) + (e2g - 1.0f) * rcpf((1.0f + eni) * (e2g + 1.0f));
  float cc = fminf(fmaxf(c, -20.0f), 20.0f);
  float e2c = __expf(2.0f * cc);
  return (e2c - 1.0f) * rcpf((1.0f + eno) * (e2c + 1.0f));
}

__device__ __forceinline__ void cell_ew(f32x4 g0, f32x4 g1, f32x4 g2, f32x4 g3,
                                        f32x4& c, _Float16* outbuf,
                                        int quad, int r16, int sl) {
  #pragma unroll
  for (int r = 0; r < 4; r++) {
    float cv = c[r];
    float hv = ew_one(g0[r], g1[r], g2[r], g3[r], cv);
    c[r] = cv;
    outbuf[(quad * 4 + r) * HPAD + sl * 16 + r16] = (_Float16)hv;
  }
}

// compact role-split helpers (FMA order identical to R10 fireH/precH/fire0/prec0)
__device__ __forceinline__ void precc(const h8 (&w)[8], h8 ar0, h8 ar1,
                                      f32x4 b, f32x4 (&ac)[4]) {
  #pragma unroll
  for (int q = 0; q < 4; q++)
    ac[q] = mf(ar1, w[q * 2 + 1], mf(ar0, w[q * 2], SPLAT(b[q])));
}
__device__ __forceinline__ void fireHc(const h8 (&w)[8], h8 ai0, h8 ai1,
                                       const f32x4 (&ac)[4], f32x4& c,
                                       _Float16* outbuf, int quad, int r16, int sl) {
  f32x4 g0 = mf(ai1, w[1], mf(ai0, w[0], ac[0]));
  f32x4 g1 = mf(ai1, w[3], mf(ai0, w[2], ac[1]));
  f32x4 g2 = mf(ai1, w[5], mf(ai0, w[4], ac[2]));
  f32x4 g3 = mf(ai1, w[7], mf(ai0, w[6], ac[3]));
  cell_ew(g0, g1, g2, g3, c, outbuf, quad, r16, sl);
}
__device__ __forceinline__ void fire0c(const h8 (&w)[4], h8 ax,
                                       const f32x4 (&ac)[4], f32x4& c,
                                       _Float16* outbuf, int quad, int r16, int sl) {
  f32x4 g0 = mf(ax, w[0], ac[0]);
  f32x4 g1 = mf(ax, w[1], ac[1]);
  f32x4 g2 = mf(ax, w[2], ac[2]);
  f32x4 g3 = mf(ax, w[3], ac[3]);
  cell_ew(g0, g1, g2, g3, c, outbuf, quad, r16, sl);
}
__device__ __forceinline__ void readA(const _Float16* buf, int r16, int quad,
                                      h8& a0, h8& a1) {
  a0 = *(const h8*)(buf + r16 * HPAD + quad * 8);
  a1 = *(const h8*)(buf + r16 * HPAD + 32 + quad * 8);
}

// ===========================================================================
// ENCODER kernel: 128 blocks x 512 threads, BB=16.  (R10 verbatim.)
// Wave (lw,grp): layer lw, col-half grp (8 n-tiles x 4 kt = 32 frags).
// 2 waves/SIMD; SIMD pairs are independent col-halves of the same layer.
// ===========================================================================
__global__ void __launch_bounds__(512, 2)
lstm_enc(const float* __restrict__ X,
         const float* __restrict__ encb,
         const h8* __restrict__ WQ,
         _Float16* __restrict__ hG,
         float* __restrict__ cG) {
  __shared__ _Float16 Hb[NL][2][16][HPAD];   // 18432 B
  __shared__ _Float16 Xb[2][16][HPAD];       //  4608 B

  const int tid  = threadIdx.x;
  const int wv   = tid >> 6;        // 0..7
  const int lane = tid & 63;
  const int quad = lane >> 4;
  const int r16  = lane & 15;
  const int grp  = wv >> 2;         // col-half
  const int lw   = wv & 3;          // layer
  const int bbase = blockIdx.x * 16;

  {
    float* p = (float*)&Hb[0][0][0][0];
    for (int i = tid; i < 4608; i += 512) p[i] = 0.0f;
    float* px = (float*)&Xb[0][0][0];
    for (int i = tid; i < 1152; i += 512) if (i < 1152) px[i] = 0.0f;
  }
  if (tid < 16 * NIN) {
    int m = tid / NIN, ii = tid - m * NIN;
    Xb[0][m][ii] = (_Float16)X[((size_t)0 * BATCH + bbase + m) * NIN + ii];
  }

  // weights: 8 n-tiles {q*4 + 2*grp + cc}, 4 k-tiles each
  h8 we[8][4];
  #pragma unroll
  for (int q = 0; q < 4; q++)
    #pragma unroll
    for (int cc = 0; cc < 2; cc++)
      #pragma unroll
      for (int kt = 0; kt < 4; kt++)
        we[q * 2 + cc][kt] =
            WQ[(PACK_H8 + PROJ_H8) +
               ((lw * 64 + (q * 4 + 2 * grp + cc) * 4 + kt) * 64 + lane)];
  float ben[8];
  #pragma unroll
  for (int q = 0; q < 4; q++)
    #pragma unroll
    for (int cc = 0; cc < 2; cc++)
      ben[q * 2 + cc] = encb[lw * 256 + q * 64 + (2 * grp + cc) * 16 + r16];

  f32x4 ce[2];
  ce[0] = SPLAT(0.f); ce[1] = SPLAT(0.f);

  // 2-deep x prefetch: wave (lw=0, grp=0), lanes 0..47, 2 floats each
  const bool pfLane = (wv == 0) && (lane < 48);
  const int  pe0 = lane * 2, pe1 = pe0 + 1;
  const int  pm0 = pe0 / NIN, pc0 = pe0 % NIN;
  const int  pm1 = pe1 / NIN, pc1 = pe1 % NIN;
  float pf0 = 0.f, pf1 = 0.f;
  if (pfLane) {
    const float* xs = X + ((size_t)1 * BATCH + bbase) * NIN;
    pf0 = xs[pe0]; pf1 = xs[pe1];
  }

  __syncthreads();

  #pragma unroll 1
  for (int i = 0; i < S_LEN + NL - 1; i++) {     // 123 intervals
    const int p = i & 1;
    const bool active = (i >= lw) && (i - lw < S_LEN);
    if (active) {
      const _Float16* inb = (lw == 0) ? &Xb[p][0][0] : &Hb[lw - 1][p ^ 1][0][0];
      const _Float16* rcb = &Hb[lw][p ^ 1][0][0];
      h8 ai0 = *(const h8*)(inb + r16 * HPAD + quad * 8);
      h8 ai1 = {};
      if (lw) ai1 = *(const h8*)(inb + r16 * HPAD + 32 + quad * 8);
      h8 ar0 = *(const h8*)(rcb + r16 * HPAD + quad * 8);
      h8 ar1 = *(const h8*)(rcb + r16 * HPAD + 32 + quad * 8);

      float nf0 = 0.f, nf1 = 0.f;
      if (pfLane && (i + 2 < S_LEN)) {
        const float* xs = X + ((size_t)(i + 2) * BATCH + bbase) * NIN;
        nf0 = xs[pe0]; nf1 = xs[pe1];
      }

      f32x4 a[8];
      #pragma unroll
      for (int j = 0; j < 8; j++) {
        f32x4 t = SPLAT(ben[j]);
        t = mf(ai0, we[j][0], t);
        if (lw) t = mf(ai1, we[j][1], t);
        t = mf(ar0, we[j][2], t);
        t = mf(ar1, we[j][3], t);
        a[j] = t;
      }

      _Float16* wb = &Hb[lw][p][0][0];
      #pragma unroll
      for (int r = 0; r < 4; r++) {
        hh2 hv;
        #pragma unroll
        for (int cc = 0; cc < 2; cc++) {
          float cv = ce[cc][r];
          hv[cc] = (_Float16)ew_one(a[cc][r], a[2 + cc][r],
                                    a[4 + cc][r], a[6 + cc][r], cv);
          ce[cc][r] = cv;
        }
        // permuted layout: col c = ct*16+r16 lands at 4*r16+ct; ct = 2*grp+cc
        *(hh2*)(wb + (quad * 4 + r) * HPAD + 4 * r16 + 2 * grp) = hv;
      }

      if (pfLane && (i + 1 < S_LEN)) {
        Xb[p ^ 1][pm0][pc0] = (_Float16)pf0;
        Xb[p ^ 1][pm1][pc1] = (_Float16)pf1;
      }
      pf0 = nf0; pf1 = nf1;
    }
    bar_lgkm();
  }

  // ---- store c to global (per-lane direct) ----
  #pragma unroll
  for (int cc = 0; cc < 2; cc++)
    #pragma unroll
    for (int r = 0; r < 4; r++)
      cG[((size_t)lw * BATCH + bbase + quad * 4 + r) * H +
         (2 * grp + cc) * 16 + r16] = ce[cc][r];

  // ---- store final h (unpermute via PI) to global ----
  #pragma unroll
  for (int u = 0; u < 8; u++) {
    int i2 = tid + u * 512;
    int c = i2 & 63, m = (i2 >> 6) & 15, l = (i2 >> 10) & 3;
    hG[((size_t)l * BATCH + bbase + m) * H + c] =
        Hb[l][(l + 1) & 1][m][PI(c)];
  }
}

// ===========================================================================
// DECODER kernel: 128 blocks x 512 threads, 8 waves = 4 col-slices x {F,P}.
// 2 waves/SIMD. F (waves 0-3): fire MFMA + ew + h-write + proj; holds fire
// frags (28) + lwA + c-state. P (waves 4-7): recurrent precompute; holds
// prec frags (32) + biases; writes ac to LDS (read by F >=1 barrier later).
// FMA accumulation order bit-identical to R10.
// ===========================================================================
__global__ void __launch_bounds__(512, 2)
lstm_dec(const float* __restrict__ X,
         const float* __restrict__ decb,
         const float* __restrict__ linb,
         const h8* __restrict__ WQ,
         const _Float16* __restrict__ hG,
         const float* __restrict__ cG,
         float* __restrict__ out) {
  __shared__ _Float16 Hb[NL][2][16][HPAD];   // 18432 B
  __shared__ f32x4 ACs[NL][4][64][4];        // 65536 B

  const int tid   = threadIdx.x;
  const int wv    = tid >> 6;        // 0..7
  const int sl    = wv & 3;          // col-slice
  const int roleP = wv >> 2;         // 0 = fire wave, 1 = prec wave
  const int lane  = tid & 63;
  const int quad  = lane >> 4;
  const int r16   = lane & 15;
  const int bbase = blockIdx.x * 16;

  // load encoder-final h into Hb[l][1] (all 512 threads)
  #pragma unroll
  for (int u = 0; u < 8; u++) {
    int i2 = tid + u * 512;
    int l = i2 >> 10, m = (i2 >> 6) & 15, c = i2 & 63;
    Hb[l][1][m][c] = hG[((size_t)l * BATCH + bbase + m) * H + c];
  }
  __syncthreads();   // h-load visible

  if (roleP) {
    // ================= P wave: recurrent precompute =================
    h8 wp0[8], wpH[3][8];
    #pragma unroll
    for (int e = 0; e < 8; e++) {
      int q = e >> 1, k = e & 1;
      wp0[e] = WQ[((FRAGS_HALF + q * 3 + 1 + k) * 4 + sl) * 64 + lane];
    }
    #pragma unroll
    for (int l = 0; l < 3; l++)
      #pragma unroll
      for (int e = 0; e < 8; e++) {
        int q = e >> 1, k = e & 1;
        wpH[l][e] = WQ[((FRAGS_HALF + 12 + l * 16 + q * 4 + 2 + k) * 4 + sl) * 64 + lane];
      }
    f32x4 b0, b1, b2, b3;
    #pragma unroll
    for (int q = 0; q < 4; q++) {
      b0[q] = decb[0 * 256 + q * 64 + sl * 16 + r16];
      b1[q] = decb[1 * 256 + q * 64 + sl * 16 + r16];
      b2[q] = decb[2 * 256 + q * 64 + sl * 16 + r16];
      b3[q] = decb[3 * 256 + q * 64 + sl * 16 + r16];
    }

    // seed: prec layers 0,1,2 from encoder-final h
    {
      h8 s0, s1;
      f32x4 a[4];
      readA(&Hb[0][1][0][0], r16, quad, s0, s1);
      precc(wp0, s0, s1, b0, a);
      #pragma unroll
      for (int j = 0; j < 4; j++) ACs[0][sl][lane][j] = a[j];
      readA(&Hb[1][1][0][0], r16, quad, s0, s1);
      precc(wpH[0], s0, s1, b1, a);
      #pragma unroll
      for (int j = 0; j < 4; j++) ACs[1][sl][lane][j] = a[j];
      readA(&Hb[2][1][0][0], r16, quad, s0, s1);
      precc(wpH[1], s0, s1, b2, a);
      #pragma unroll
      for (int j = 0; j < 4; j++) ACs[2][sl][lane][j] = a[j];
    }
    bar_lgkm();   // matches F's pre-loop bar

    #pragma unroll 1
    for (int t = 0; t < TLEN; t++) {
      const int cur = t & 1, prv = cur ^ 1;
      { // ---- A: prec layer3 from h3[prv] ----
        h8 a0, a1; readA(&Hb[3][prv][0][0], r16, quad, a0, a1);
        f32x4 a[4]; precc(wpH[2], a0, a1, b3, a);
        #pragma unroll
        for (int j = 0; j < 4; j++) ACs[3][sl][lane][j] = a[j];
        bar_lgkm();
      }
      { // ---- B: prec layer0 from h0[cur] ----
        h8 a0, a1; readA(&Hb[0][cur][0][0], r16, quad, a0, a1);
        f32x4 a[4]; precc(wp0, a0, a1, b0, a);
        #pragma unroll
        for (int j = 0; j < 4; j++) ACs[0][sl][lane][j] = a[j];
        bar_lgkm();
      }
      { // ---- C: prec layer1 from h1[cur] ----
        h8 a0, a1; readA(&Hb[1][cur][0][0], r16, quad, a0, a1);
        f32x4 a[4]; precc(wpH[0], a0, a1, b1, a);
        #pragma unroll
        for (int j = 0; j < 4; j++) ACs[1][sl][lane][j] = a[j];
        bar_lgkm();
      }
      { // ---- D: prec layer2 from h2[cur] ----
        h8 a0, a1; readA(&Hb[2][cur][0][0], r16, quad, a0, a1);
        f32x4 a[4]; precc(wpH[1], a0, a1, b2, a);
        #pragma unroll
        for (int j = 0; j < 4; j++) ACs[2][sl][lane][j] = a[j];
        bar_lgkm();
      }
    }
  } else {
    // ================= F wave: fire + ew + proj =================
    h8 wf0[4], wfH[3][8];
    #pragma unroll
    for (int q = 0; q < 4; q++)
      wf0[q] = WQ[((FRAGS_HALF + q * 3) * 4 + sl) * 64 + lane];
    #pragma unroll
    for (int l = 0; l < 3; l++)
      #pragma unroll
      for (int e = 0; e < 8; e++) {
        int q = e >> 1, k = e & 1;
        wfH[l][e] = WQ[((FRAGS_HALF + 12 + l * 16 + q * 4 + k) * 4 + sl) * 64 + lane];
      }

    // c slices
    f32x4 cs0, cs1, cs2, cs3;
    #pragma unroll
    for (int r = 0; r < 4; r++) {
      cs0[r] = cG[((size_t)0 * BATCH + bbase + quad * 4 + r) * H + sl * 16 + r16];
      cs1[r] = cG[((size_t)1 * BATCH + bbase + quad * 4 + r) * H + sl * 16 + r16];
      cs2[r] = cG[((size_t)2 * BATCH + bbase + quad * 4 + r) * H + sl * 16 + r16];
      cs3[r] = cG[((size_t)3 * BATCH + bbase + quad * 4 + r) * H + sl * 16 + r16];
    }

    h8 lwA0 = WQ[PACK_H8 + lane];
    h8 lwA1 = WQ[PACK_H8 + 64 + lane];
    f32x4 lbq;
    #pragma unroll
    for (int r = 0; r < 4; r++)
      lbq[r] = (quad * 4 + r < NIN) ? linb[quad * 4 + r] : 0.0f;

    // x[119] A-frag (k = quad*8+j; only k<6 real)
    h8 xseed = {};
    if (quad == 0) {
      const float* xs = X + ((size_t)(S_LEN - 1) * BATCH + bbase + r16) * NIN;
      #pragma unroll
      for (int j = 0; j < 6; j++) xseed[j] = (_Float16)xs[j];
    }

    bar_lgkm();   // matches P's seed bar

    #pragma unroll 1
    for (int t = 0; t < TLEN; t++) {
      const int cur = t & 1, prv = cur ^ 1;
      { // ---- A: proj(h3[t-1]) + layer-0 fire ----
        h8 ar0, ar1;
        readA(&Hb[3][prv][0][0], r16, quad, ar0, ar1);
        h8 ax;
        if (t == 0) {
          ax = xseed;
        } else {
          f32x4 ap = lbq;
          ap = mf(lwA0, ar0, ap);     // A = linW (m=feature), B = h3 (n=batch)
          ap = mf(lwA1, ar1, ap);
          if (sl == 0) {
            #pragma unroll
            for (int r = 0; r < 4; r++) {
              const int fm = quad * 4 + r;
              if (fm < NIN)
                out[((size_t)(t - 1) * BATCH + bbase + r16) * NIN + fm] = ap[r];
            }
          }
          float x0 = __shfl(ap[0], r16);
          float x1 = __shfl(ap[1], r16);
          float x2 = __shfl(ap[2], r16);
          float x3 = __shfl(ap[3], r16);
          float x4 = __shfl(ap[0], 16 + r16);
          float x5 = __shfl(ap[1], 16 + r16);
          h8 xa = {};
          xa[0] = (_Float16)x0; xa[1] = (_Float16)x1; xa[2] = (_Float16)x2;
          xa[3] = (_Float16)x3; xa[4] = (_Float16)x4; xa[5] = (_Float16)x5;
          h8 zz = {};
          ax = (quad == 0) ? xa : zz;
        }
        f32x4 ac[4];
        #pragma unroll
        for (int j = 0; j < 4; j++) ac[j] = ACs[0][sl][lane][j];
        fire0c(wf0, ax, ac, cs0, &Hb[0][cur][0][0], quad, r16, sl);
        bar_lgkm();
      }
      { // ---- B: fire layer1 ----
        h8 ai0, ai1;
        readA(&Hb[0][cur][0][0], r16, quad, ai0, ai1);
        f32x4 ac[4];
        #pragma unroll
        for (int j = 0; j < 4; j++) ac[j] = ACs[1][sl][lane][j];
        fireHc(wfH[0], ai0, ai1, ac, cs1, &Hb[1][cur][0][0], quad, r16, sl);
        bar_lgkm();
      }
      { // ---- C: fire layer2 ----
        h8 ai0, ai1;
        readA(&Hb[1][cur][0][0], r16, quad, ai0, ai1);
        f32x4 ac[4];
        #pragma unroll
        for (int j = 0; j < 4; j++) ac[j] = ACs[2][sl][lane][j];
        fireHc(wfH[1], ai0, ai1, ac, cs2, &Hb[2][cur][0][0], quad, r16, sl);
        bar_lgkm();
      }
      { // ---- D: fire layer3 ----
        h8 ai0, ai1;
        readA(&Hb[2][cur][0][0], r16, quad, ai0, ai1);
        f32x4 ac[4];
        #pragma unroll
        for (int j = 0; j < 4; j++) ac[j] = ACs[3][sl][lane][j];
        fireHc(wfH[2], ai0, ai1, ac, cs3, &Hb[3][cur][0][0], quad, r16, sl);
        bar_lgkm();
      }
    }

    // epilogue: out[TLEN-1] from h3 of last step (parity 1)
    if (sl == 0) {
      h8 ar0, ar1;
      readA(&Hb[3][1][0][0], r16, quad, ar0, ar1);
      f32x4 ap = lbq;
      ap = mf(lwA0, ar0, ap);
      ap = mf(lwA1, ar1, ap);
      #pragma unroll
      for (int r = 0; r < 4; r++) {
        const int fm = quad * 4 + r;
        if (fm < NIN)
          out[((size_t)(TLEN - 1) * BATCH + bbase + r16) * NIN + fm] = ap[r];
      }
    }
  }
}

// ---------------------------------------------------------------------------
extern "C" void kernel_launch(void* const* d_in, const int* in_sizes, int n_in,
                              void* d_out, int out_size, void* d_ws, size_t ws_size,
                              hipStream_t stream) {
  const float* X     = (const float*)d_in[0];
  const float* eWih0 = (const float*)d_in[1];
  const float* eWih  = (const float*)d_in[2];
  const float* eWhh  = (const float*)d_in[3];
  const float* eb    = (const float*)d_in[4];
  const float* dWih0 = (const float*)d_in[5];
  const float* dWih  = (const float*)d_in[6];
  const float* dWhh  = (const float*)d_in[7];
  const float* db    = (const float*)d_in[8];
  const float* lW    = (const float*)d_in[9];
  const float* lb    = (const float*)d_in[10];

  _Float16* wq = (_Float16*)d_ws;
  _Float16* hG = (_Float16*)((char*)d_ws + WS_HOFF);
  float*    cG = (float*)((char*)d_ws + WS_COFF);

  prep_weights<<<(NTOT + 255) / 256, 256, 0, stream>>>(
      eWih0, eWih, eWhh, dWih0, dWih, dWhh, lW, wq);

  lstm_enc<<<BATCH / 16, 512, 0, stream>>>(
      X, eb, (const h8*)wq, hG, cG);

  lstm_dec<<<BATCH / 16, 512, 0, stream>>>(
      X, db, lb, (const h8*)wq, hG, cG, (float*)d_out);
}

// Round 3
// 536.636 us; speedup vs baseline: 1.1719x; 1.1268x over previous
//
#include <hip/hip_runtime.h>

// ---------------------------------------------------------------------------
// Round 13: R12 structure with the AC handoff buffer transposed to
//   lane-contiguous layout. R12's ACs[l][sl][lane][4] had a 64 B lane stride
//   -> 32-way LDS bank conflicts (SQ_LDS_BANK_CONFLICT 20x, 39.5M) on the
//   8 b128 AC ops per interval. New layout ACs[l][sl][j][lane] has 16 B lane
//   stride = canonical minimal-aliasing b128 pattern.
//   Everything else identical to R12 (absmax canary: 4.8828e-4).
// ---------------------------------------------------------------------------

#define S_LEN 120
#define BATCH 2048
#define NIN   6
#define H     64
#define NL    4
#define TLEN  120

#define HPAD 72            // row stride in halves (144 B)

#define FRAGS_HALF 60      // col-sliced: 12 (layer0) + 3*16
#define PACK_H8    (2 * FRAGS_HALF * 4 * 64)
#define PROJ_H8    (2 * 64)
#define NPACK      ((PACK_H8 + PROJ_H8) * 8)   // 246784 fp16 elements
#define EPACK_EL   (256 * 64 * 8)              // encoder pipeline pack
#define NTOT       (NPACK + EPACK_EL)          // 377856 (~756 KB)

// workspace byte offsets (after the weight pack)
#define WS_HOFF (768 * 1024)                   // h: 4*2048*64 fp16 = 1 MB
#define WS_COFF (WS_HOFF + 1024 * 1024)        // c: 4*2048*64 f32 = 2 MB

#define PERM(kk) ((((kk) & 3) << 4) | ((kk) >> 2))   // pi^-1
#define PI(c)    ((((c) & 15) << 2) | ((c) >> 4))    // pi

typedef _Float16 h8    __attribute__((ext_vector_type(8)));
typedef _Float16 hh2   __attribute__((ext_vector_type(2)));
typedef float    f32x4 __attribute__((ext_vector_type(4)));

__device__ __forceinline__ void bar_lgkm() {
  asm volatile("s_waitcnt lgkmcnt(0)\n\ts_barrier" ::: "memory");
}

// ---------------------------------------------------------------------------
// Weight pack (identical to rounds 5-12).
// ---------------------------------------------------------------------------
__global__ void prep_weights(const float* __restrict__ eWih0,
                             const float* __restrict__ eWih,
                             const float* __restrict__ eWhh,
                             const float* __restrict__ dWih0,
                             const float* __restrict__ dWih,
                             const float* __restrict__ dWhh,
                             const float* __restrict__ linW,
                             _Float16* __restrict__ wq) {
  int idx = blockIdx.x * blockDim.x + threadIdx.x;
  if (idx >= NTOT) return;

  if (idx >= NPACK) {                      // ---- encoder pipeline pack ----
    int p    = idx - NPACK;
    int j    = p & 7;
    int lane = (p >> 3) & 63;
    int fe   = p >> 9;
    int kt   = fe & 3, nt = (fe >> 2) & 15, l = fe >> 6;
    int g    = nt * 16 + (lane & 15);
    int koff = ((lane >> 4) << 3) + j;
    float v = 0.0f;
    if (l == 0) {
      if (kt == 0)      v = (koff < NIN) ? eWih0[g * NIN + koff] : 0.0f;
      else if (kt == 1) v = 0.0f;
      else { int kk = (kt - 2) * 32 + koff; v = eWhh[g * H + PERM(kk)]; }
    } else {
      if (kt < 2) { int kk = kt * 32 + koff;
                    v = eWih[((l - 1) * 256 + g) * H + PERM(kk)]; }
      else        { int kk = (kt - 2) * 32 + koff;
                    v = eWhh[(l * 256 + g) * H + PERM(kk)]; }
    }
    wq[idx] = (_Float16)v;
    return;
  }

  if (idx >= PACK_H8 * 8) {                // ---- linW A-layout frags ----
    int p    = idx - PACK_H8 * 8;
    int j    = p & 7;
    int lane = (p >> 3) & 63;
    int fr   = p >> 9;
    int m    = lane & 15;
    int k    = fr * 32 + ((lane >> 4) << 3) + j;
    wq[idx] = (_Float16)((m < NIN) ? linW[m * H + k] : 0.0f);
    return;
  }

  // ---- col-sliced pack (decoder uses dec half) ----
  const int j    = idx & 7;
  const int lane = (idx >> 3) & 63;
  const int wv   = (idx >> 9) & 3;
  const int fh   = idx >> 11;
  const int f    = fh % FRAGS_HALF;
  const int half = fh / FRAGS_HALF;
  const float* Wi0 = half ? dWih0 : eWih0;
  const float* Wi  = half ? dWih  : eWih;
  const float* Wh  = half ? dWhh  : eWhh;
  int l, q, kt;
  if (f < 12) { l = 0; q = f / 3; kt = f % 3; }
  else        { int ff = f - 12; l = 1 + ff / 16; ff %= 16; q = ff / 4; kt = ff % 4; }
  const int g    = q * 64 + wv * 16 + (lane & 15);
  const int k_in = ((lane >> 4) << 3) + j;
  float v;
  if (l == 0) {
    if (kt == 0) v = (k_in < NIN) ? Wi0[g * NIN + k_in] : 0.0f;
    else         v = Wh[g * H + (kt - 1) * 32 + k_in];
  } else {
    if (kt < 2) v = Wi[((l - 1) * 256 + g) * H + kt * 32 + k_in];
    else        v = Wh[(l * 256 + g) * H + (kt - 2) * 32 + k_in];
  }
  wq[idx] = (_Float16)v;
}

// ---------------------------------------------------------------------------
__device__ __forceinline__ float rcpf(float x) { return __builtin_amdgcn_rcpf(x); }
__device__ __forceinline__ f32x4 mf(h8 a, h8 b, f32x4 c) {
  return __builtin_amdgcn_mfma_f32_16x16x32_f16(a, b, c, 0, 0, 0);
}
#define SPLAT(v) ((f32x4){(v), (v), (v), (v)})

// merged-rcp LSTM cell: 5 exp + 3 rcp (+2 clamps); absmax-validated R6-R12.
__device__ __forceinline__ float ew_one(float gi, float gf, float gg, float go,
                                        float& c) {
  gg = fminf(fmaxf(gg, -20.0f), 20.0f);
  float eni = __expf(-gi);
  float e2g = __expf(2.0f * gg);
  float enf = __expf(-gf);
  float eno = __expf(-go);
  c = c * rcpf(1.0f + enf) + (e2g - 1.0f) * rcpf((1.0f + eni) * (e2g + 1.0f));
  float cc = fminf(fmaxf(c, -20.0f), 20.0f);
  float e2c = __expf(2.0f * cc);
  return (e2c - 1.0f) * rcpf((1.0f + eno) * (e2c + 1.0f));
}

__device__ __forceinline__ void cell_ew(f32x4 g0, f32x4 g1, f32x4 g2, f32x4 g3,
                                        f32x4& c, _Float16* outbuf,
                                        int quad, int r16, int sl) {
  #pragma unroll
  for (int r = 0; r < 4; r++) {
    float cv = c[r];
    float hv = ew_one(g0[r], g1[r], g2[r], g3[r], cv);
    c[r] = cv;
    outbuf[(quad * 4 + r) * HPAD + sl * 16 + r16] = (_Float16)hv;
  }
}

// compact role-split helpers (FMA order identical to R10 fireH/precH/fire0/prec0)
__device__ __forceinline__ void precc(const h8 (&w)[8], h8 ar0, h8 ar1,
                                      f32x4 b, f32x4 (&ac)[4]) {
  #pragma unroll
  for (int q = 0; q < 4; q++)
    ac[q] = mf(ar1, w[q * 2 + 1], mf(ar0, w[q * 2], SPLAT(b[q])));
}
__device__ __forceinline__ void fireHc(const h8 (&w)[8], h8 ai0, h8 ai1,
                                       const f32x4 (&ac)[4], f32x4& c,
                                       _Float16* outbuf, int quad, int r16, int sl) {
  f32x4 g0 = mf(ai1, w[1], mf(ai0, w[0], ac[0]));
  f32x4 g1 = mf(ai1, w[3], mf(ai0, w[2], ac[1]));
  f32x4 g2 = mf(ai1, w[5], mf(ai0, w[4], ac[2]));
  f32x4 g3 = mf(ai1, w[7], mf(ai0, w[6], ac[3]));
  cell_ew(g0, g1, g2, g3, c, outbuf, quad, r16, sl);
}
__device__ __forceinline__ void fire0c(const h8 (&w)[4], h8 ax,
                                       const f32x4 (&ac)[4], f32x4& c,
                                       _Float16* outbuf, int quad, int r16, int sl) {
  f32x4 g0 = mf(ax, w[0], ac[0]);
  f32x4 g1 = mf(ax, w[1], ac[1]);
  f32x4 g2 = mf(ax, w[2], ac[2]);
  f32x4 g3 = mf(ax, w[3], ac[3]);
  cell_ew(g0, g1, g2, g3, c, outbuf, quad, r16, sl);
}
__device__ __forceinline__ void readA(const _Float16* buf, int r16, int quad,
                                      h8& a0, h8& a1) {
  a0 = *(const h8*)(buf + r16 * HPAD + quad * 8);
  a1 = *(const h8*)(buf + r16 * HPAD + 32 + quad * 8);
}

// ===========================================================================
// ENCODER kernel: 128 blocks x 512 threads, BB=16.  (R10 verbatim.)
// ===========================================================================
__global__ void __launch_bounds__(512, 2)
lstm_enc(const float* __restrict__ X,
         const float* __restrict__ encb,
         const h8* __restrict__ WQ,
         _Float16* __restrict__ hG,
         float* __restrict__ cG) {
  __shared__ _Float16 Hb[NL][2][16][HPAD];   // 18432 B
  __shared__ _Float16 Xb[2][16][HPAD];       //  4608 B

  const int tid  = threadIdx.x;
  const int wv   = tid >> 6;        // 0..7
  const int lane = tid & 63;
  const int quad = lane >> 4;
  const int r16  = lane & 15;
  const int grp  = wv >> 2;         // col-half
  const int lw   = wv & 3;          // layer
  const int bbase = blockIdx.x * 16;

  {
    float* p = (float*)&Hb[0][0][0][0];
    for (int i = tid; i < 4608; i += 512) p[i] = 0.0f;
    float* px = (float*)&Xb[0][0][0];
    for (int i = tid; i < 1152; i += 512) if (i < 1152) px[i] = 0.0f;
  }
  if (tid < 16 * NIN) {
    int m = tid / NIN, ii = tid - m * NIN;
    Xb[0][m][ii] = (_Float16)X[((size_t)0 * BATCH + bbase + m) * NIN + ii];
  }

  // weights: 8 n-tiles {q*4 + 2*grp + cc}, 4 k-tiles each
  h8 we[8][4];
  #pragma unroll
  for (int q = 0; q < 4; q++)
    #pragma unroll
    for (int cc = 0; cc < 2; cc++)
      #pragma unroll
      for (int kt = 0; kt < 4; kt++)
        we[q * 2 + cc][kt] =
            WQ[(PACK_H8 + PROJ_H8) +
               ((lw * 64 + (q * 4 + 2 * grp + cc) * 4 + kt) * 64 + lane)];
  float ben[8];
  #pragma unroll
  for (int q = 0; q < 4; q++)
    #pragma unroll
    for (int cc = 0; cc < 2; cc++)
      ben[q * 2 + cc] = encb[lw * 256 + q * 64 + (2 * grp + cc) * 16 + r16];

  f32x4 ce[2];
  ce[0] = SPLAT(0.f); ce[1] = SPLAT(0.f);

  // 2-deep x prefetch: wave (lw=0, grp=0), lanes 0..47, 2 floats each
  const bool pfLane = (wv == 0) && (lane < 48);
  const int  pe0 = lane * 2, pe1 = pe0 + 1;
  const int  pm0 = pe0 / NIN, pc0 = pe0 % NIN;
  const int  pm1 = pe1 / NIN, pc1 = pe1 % NIN;
  float pf0 = 0.f, pf1 = 0.f;
  if (pfLane) {
    const float* xs = X + ((size_t)1 * BATCH + bbase) * NIN;
    pf0 = xs[pe0]; pf1 = xs[pe1];
  }

  __syncthreads();

  #pragma unroll 1
  for (int i = 0; i < S_LEN + NL - 1; i++) {     // 123 intervals
    const int p = i & 1;
    const bool active = (i >= lw) && (i - lw < S_LEN);
    if (active) {
      const _Float16* inb = (lw == 0) ? &Xb[p][0][0] : &Hb[lw - 1][p ^ 1][0][0];
      const _Float16* rcb = &Hb[lw][p ^ 1][0][0];
      h8 ai0 = *(const h8*)(inb + r16 * HPAD + quad * 8);
      h8 ai1 = {};
      if (lw) ai1 = *(const h8*)(inb + r16 * HPAD + 32 + quad * 8);
      h8 ar0 = *(const h8*)(rcb + r16 * HPAD + quad * 8);
      h8 ar1 = *(const h8*)(rcb + r16 * HPAD + 32 + quad * 8);

      float nf0 = 0.f, nf1 = 0.f;
      if (pfLane && (i + 2 < S_LEN)) {
        const float* xs = X + ((size_t)(i + 2) * BATCH + bbase) * NIN;
        nf0 = xs[pe0]; nf1 = xs[pe1];
      }

      f32x4 a[8];
      #pragma unroll
      for (int j = 0; j < 8; j++) {
        f32x4 t = SPLAT(ben[j]);
        t = mf(ai0, we[j][0], t);
        if (lw) t = mf(ai1, we[j][1], t);
        t = mf(ar0, we[j][2], t);
        t = mf(ar1, we[j][3], t);
        a[j] = t;
      }

      _Float16* wb = &Hb[lw][p][0][0];
      #pragma unroll
      for (int r = 0; r < 4; r++) {
        hh2 hv;
        #pragma unroll
        for (int cc = 0; cc < 2; cc++) {
          float cv = ce[cc][r];
          hv[cc] = (_Float16)ew_one(a[cc][r], a[2 + cc][r],
                                    a[4 + cc][r], a[6 + cc][r], cv);
          ce[cc][r] = cv;
        }
        // permuted layout: col c = ct*16+r16 lands at 4*r16+ct; ct = 2*grp+cc
        *(hh2*)(wb + (quad * 4 + r) * HPAD + 4 * r16 + 2 * grp) = hv;
      }

      if (pfLane && (i + 1 < S_LEN)) {
        Xb[p ^ 1][pm0][pc0] = (_Float16)pf0;
        Xb[p ^ 1][pm1][pc1] = (_Float16)pf1;
      }
      pf0 = nf0; pf1 = nf1;
    }
    bar_lgkm();
  }

  // ---- store c to global (per-lane direct) ----
  #pragma unroll
  for (int cc = 0; cc < 2; cc++)
    #pragma unroll
    for (int r = 0; r < 4; r++)
      cG[((size_t)lw * BATCH + bbase + quad * 4 + r) * H +
         (2 * grp + cc) * 16 + r16] = ce[cc][r];

  // ---- store final h (unpermute via PI) to global ----
  #pragma unroll
  for (int u = 0; u < 8; u++) {
    int i2 = tid + u * 512;
    int c = i2 & 63, m = (i2 >> 6) & 15, l = (i2 >> 10) & 3;
    hG[((size_t)l * BATCH + bbase + m) * H + c] =
        Hb[l][(l + 1) & 1][m][PI(c)];
  }
}

// ===========================================================================
// DECODER kernel: 128 blocks x 512 threads, 8 waves = 4 col-slices x {F,P}.
// 2 waves/SIMD. AC handoff via lane-contiguous LDS (16 B lane stride).
// FMA accumulation order bit-identical to R10.
// ===========================================================================
__global__ void __launch_bounds__(512, 2)
lstm_dec(const float* __restrict__ X,
         const float* __restrict__ decb,
         const float* __restrict__ linb,
         const h8* __restrict__ WQ,
         const _Float16* __restrict__ hG,
         const float* __restrict__ cG,
         float* __restrict__ out) {
  __shared__ _Float16 Hb[NL][2][16][HPAD];   // 18432 B
  __shared__ f32x4 ACs[NL][4][4][64];        // 65536 B, [l][sl][j][lane]

  const int tid   = threadIdx.x;
  const int wv    = tid >> 6;        // 0..7
  const int sl    = wv & 3;          // col-slice
  const int roleP = wv >> 2;         // 0 = fire wave, 1 = prec wave
  const int lane  = tid & 63;
  const int quad  = lane >> 4;
  const int r16   = lane & 15;
  const int bbase = blockIdx.x * 16;

  // load encoder-final h into Hb[l][1] (all 512 threads)
  #pragma unroll
  for (int u = 0; u < 8; u++) {
    int i2 = tid + u * 512;
    int l = i2 >> 10, m = (i2 >> 6) & 15, c = i2 & 63;
    Hb[l][1][m][c] = hG[((size_t)l * BATCH + bbase + m) * H + c];
  }
  __syncthreads();   // h-load visible

  if (roleP) {
    // ================= P wave: recurrent precompute =================
    h8 wp0[8], wpH[3][8];
    #pragma unroll
    for (int e = 0; e < 8; e++) {
      int q = e >> 1, k = e & 1;
      wp0[e] = WQ[((FRAGS_HALF + q * 3 + 1 + k) * 4 + sl) * 64 + lane];
    }
    #pragma unroll
    for (int l = 0; l < 3; l++)
      #pragma unroll
      for (int e = 0; e < 8; e++) {
        int q = e >> 1, k = e & 1;
        wpH[l][e] = WQ[((FRAGS_HALF + 12 + l * 16 + q * 4 + 2 + k) * 4 + sl) * 64 + lane];
      }
    f32x4 b0, b1, b2, b3;
    #pragma unroll
    for (int q = 0; q < 4; q++) {
      b0[q] = decb[0 * 256 + q * 64 + sl * 16 + r16];
      b1[q] = decb[1 * 256 + q * 64 + sl * 16 + r16];
      b2[q] = decb[2 * 256 + q * 64 + sl * 16 + r16];
      b3[q] = decb[3 * 256 + q * 64 + sl * 16 + r16];
    }

    // seed: prec layers 0,1,2 from encoder-final h
    {
      h8 s0, s1;
      f32x4 a[4];
      readA(&Hb[0][1][0][0], r16, quad, s0, s1);
      precc(wp0, s0, s1, b0, a);
      #pragma unroll
      for (int j = 0; j < 4; j++) ACs[0][sl][j][lane] = a[j];
      readA(&Hb[1][1][0][0], r16, quad, s0, s1);
      precc(wpH[0], s0, s1, b1, a);
      #pragma unroll
      for (int j = 0; j < 4; j++) ACs[1][sl][j][lane] = a[j];
      readA(&Hb[2][1][0][0], r16, quad, s0, s1);
      precc(wpH[1], s0, s1, b2, a);
      #pragma unroll
      for (int j = 0; j < 4; j++) ACs[2][sl][j][lane] = a[j];
    }
    bar_lgkm();   // matches F's pre-loop bar

    #pragma unroll 1
    for (int t = 0; t < TLEN; t++) {
      const int cur = t & 1, prv = cur ^ 1;
      { // ---- A: prec layer3 from h3[prv] ----
        h8 a0, a1; readA(&Hb[3][prv][0][0], r16, quad, a0, a1);
        f32x4 a[4]; precc(wpH[2], a0, a1, b3, a);
        #pragma unroll
        for (int j = 0; j < 4; j++) ACs[3][sl][j][lane] = a[j];
        bar_lgkm();
      }
      { // ---- B: prec layer0 from h0[cur] ----
        h8 a0, a1; readA(&Hb[0][cur][0][0], r16, quad, a0, a1);
        f32x4 a[4]; precc(wp0, a0, a1, b0, a);
        #pragma unroll
        for (int j = 0; j < 4; j++) ACs[0][sl][j][lane] = a[j];
        bar_lgkm();
      }
      { // ---- C: prec layer1 from h1[cur] ----
        h8 a0, a1; readA(&Hb[1][cur][0][0], r16, quad, a0, a1);
        f32x4 a[4]; precc(wpH[0], a0, a1, b1, a);
        #pragma unroll
        for (int j = 0; j < 4; j++) ACs[1][sl][j][lane] = a[j];
        bar_lgkm();
      }
      { // ---- D: prec layer2 from h2[cur] ----
        h8 a0, a1; readA(&Hb[2][cur][0][0], r16, quad, a0, a1);
        f32x4 a[4]; precc(wpH[1], a0, a1, b2, a);
        #pragma unroll
        for (int j = 0; j < 4; j++) ACs[2][sl][j][lane] = a[j];
        bar_lgkm();
      }
    }
  } else {
    // ================= F wave: fire + ew + proj =================
    h8 wf0[4], wfH[3][8];
    #pragma unroll
    for (int q = 0; q < 4; q++)
      wf0[q] = WQ[((FRAGS_HALF + q * 3) * 4 + sl) * 64 + lane];
    #pragma unroll
    for (int l = 0; l < 3; l++)
      #pragma unroll
      for (int e = 0; e < 8; e++) {
        int q = e >> 1, k = e & 1;
        wfH[l][e] = WQ[((FRAGS_HALF + 12 + l * 16 + q * 4 + k) * 4 + sl) * 64 + lane];
      }

    // c slices
    f32x4 cs0, cs1, cs2, cs3;
    #pragma unroll
    for (int r = 0; r < 4; r++) {
      cs0[r] = cG[((size_t)0 * BATCH + bbase + quad * 4 + r) * H + sl * 16 + r16];
      cs1[r] = cG[((size_t)1 * BATCH + bbase + quad * 4 + r) * H + sl * 16 + r16];
      cs2[r] = cG[((size_t)2 * BATCH + bbase + quad * 4 + r) * H + sl * 16 + r16];
      cs3[r] = cG[((size_t)3 * BATCH + bbase + quad * 4 + r) * H + sl * 16 + r16];
    }

    h8 lwA0 = WQ[PACK_H8 + lane];
    h8 lwA1 = WQ[PACK_H8 + 64 + lane];
    f32x4 lbq;
    #pragma unroll
    for (int r = 0; r < 4; r++)
      lbq[r] = (quad * 4 + r < NIN) ? linb[quad * 4 + r] : 0.0f;

    // x[119] A-frag (k = quad*8+j; only k<6 real)
    h8 xseed = {};
    if (quad == 0) {
      const float* xs = X + ((size_t)(S_LEN - 1) * BATCH + bbase + r16) * NIN;
      #pragma unroll
      for (int j = 0; j < 6; j++) xseed[j] = (_Float16)xs[j];
    }

    bar_lgkm();   // matches P's seed bar

    #pragma unroll 1
    for (int t = 0; t < TLEN; t++) {
      const int cur = t & 1, prv = cur ^ 1;
      { // ---- A: proj(h3[t-1]) + layer-0 fire ----
        h8 ar0, ar1;
        readA(&Hb[3][prv][0][0], r16, quad, ar0, ar1);
        h8 ax;
        if (t == 0) {
          ax = xseed;
        } else {
          f32x4 ap = lbq;
          ap = mf(lwA0, ar0, ap);     // A = linW (m=feature), B = h3 (n=batch)
          ap = mf(lwA1, ar1, ap);
          if (sl == 0) {
            #pragma unroll
            for (int r = 0; r < 4; r++) {
              const int fm = quad * 4 + r;
              if (fm < NIN)
                out[((size_t)(t - 1) * BATCH + bbase + r16) * NIN + fm] = ap[r];
            }
          }
          float x0 = __shfl(ap[0], r16);
          float x1 = __shfl(ap[1], r16);
          float x2 = __shfl(ap[2], r16);
          float x3 = __shfl(ap[3], r16);
          float x4 = __shfl(ap[0], 16 + r16);
          float x5 = __shfl(ap[1], 16 + r16);
          h8 xa = {};
          xa[0] = (_Float16)x0; xa[1] = (_Float16)x1; xa[2] = (_Float16)x2;
          xa[3] = (_Float16)x3; xa[4] = (_Float16)x4; xa[5] = (_Float16)x5;
          h8 zz = {};
          ax = (quad == 0) ? xa : zz;
        }
        f32x4 ac[4];
        #pragma unroll
        for (int j = 0; j < 4; j++) ac[j] = ACs[0][sl][j][lane];
        fire0c(wf0, ax, ac, cs0, &Hb[0][cur][0][0], quad, r16, sl);
        bar_lgkm();
      }
      { // ---- B: fire layer1 ----
        h8 ai0, ai1;
        readA(&Hb[0][cur][0][0], r16, quad, ai0, ai1);
        f32x4 ac[4];
        #pragma unroll
        for (int j = 0; j < 4; j++) ac[j] = ACs[1][sl][j][lane];
        fireHc(wfH[0], ai0, ai1, ac, cs1, &Hb[1][cur][0][0], quad, r16, sl);
        bar_lgkm();
      }
      { // ---- C: fire layer2 ----
        h8 ai0, ai1;
        readA(&Hb[1][cur][0][0], r16, quad, ai0, ai1);
        f32x4 ac[4];
        #pragma unroll
        for (int j = 0; j < 4; j++) ac[j] = ACs[2][sl][j][lane];
        fireHc(wfH[1], ai0, ai1, ac, cs2, &Hb[2][cur][0][0], quad, r16, sl);
        bar_lgkm();
      }
      { // ---- D: fire layer3 ----
        h8 ai0, ai1;
        readA(&Hb[2][cur][0][0], r16, quad, ai0, ai1);
        f32x4 ac[4];
        #pragma unroll
        for (int j = 0; j < 4; j++) ac[j] = ACs[3][sl][j][lane];
        fireHc(wfH[2], ai0, ai1, ac, cs3, &Hb[3][cur][0][0], quad, r16, sl);
        bar_lgkm();
      }
    }

    // epilogue: out[TLEN-1] from h3 of last step (parity 1)
    if (sl == 0) {
      h8 ar0, ar1;
      readA(&Hb[3][1][0][0], r16, quad, ar0, ar1);
      f32x4 ap = lbq;
      ap = mf(lwA0, ar0, ap);
      ap = mf(lwA1, ar1, ap);
      #pragma unroll
      for (int r = 0; r < 4; r++) {
        const int fm = quad * 4 + r;
        if (fm < NIN)
          out[((size_t)(TLEN - 1) * BATCH + bbase + r16) * NIN + fm] = ap[r];
      }
    }
  }
}

// ---------------------------------------------------------------------------
extern "C" void kernel_launch(void* const* d_in, const int* in_sizes, int n_in,
                              void* d_out, int out_size, void* d_ws, size_t ws_size,
                              hipStream_t stream) {
  const float* X     = (const float*)d_in[0];
  const float* eWih0 = (const float*)d_in[1];
  const float* eWih  = (const float*)d_in[2];
  const float* eWhh  = (const float*)d_in[3];
  const float* eb    = (const float*)d_in[4];
  const float* dWih0 = (const float*)d_in[5];
  const float* dWih  = (const float*)d_in[6];
  const float* dWhh  = (const float*)d_in[7];
  const float* db    = (const float*)d_in[8];
  const float* lW    = (const float*)d_in[9];
  const float* lb    = (const float*)d_in[10];

  _Float16* wq = (_Float16*)d_ws;
  _Float16* hG = (_Float16*)((char*)d_ws + WS_HOFF);
  float*    cG = (float*)((char*)d_ws + WS_COFF);

  prep_weights<<<(NTOT + 255) / 256, 256, 0, stream>>>(
      eWih0, eWih, eWhh, dWih0, dWih, dWhh, lW, wq);

  lstm_enc<<<BATCH / 16, 512, 0, stream>>>(
      X, eb, (const h8*)wq, hG, cG);

  lstm_dec<<<BATCH / 16, 512, 0, stream>>>(
      X, db, lb, (const h8*)wq, hG, cG, (float*)d_out);
}

// Round 4
// 531.830 us; speedup vs baseline: 1.1825x; 1.0090x over previous
//
#include <hip/hip_runtime.h>

// ---------------------------------------------------------------------------
// Round 14: decoder polish on the validated R13 F/P-split structure.
//  (1) F-waves run at s_setprio(1): per-SIMD role diversity (1F+1P) is the
//      T5-pays regime; F's ew chain gates every barrier.
//  (2) interval-A xa build: 6 ds_bpermute (__shfl) -> 2 ds_swizzle xor-16
//      + 4 register copies (shfl(ap[r], r16) is identity for the quad==0
//      consumers). Bit-identical data movement.
//  Encoder (R10) and P-wave untouched. absmax canary: 4.8828e-4.
// ---------------------------------------------------------------------------

#define S_LEN 120
#define BATCH 2048
#define NIN   6
#define H     64
#define NL    4
#define TLEN  120

#define HPAD 72            // row stride in halves (144 B)

#define FRAGS_HALF 60      // col-sliced: 12 (layer0) + 3*16
#define PACK_H8    (2 * FRAGS_HALF * 4 * 64)
#define PROJ_H8    (2 * 64)
#define NPACK      ((PACK_H8 + PROJ_H8) * 8)   // 246784 fp16 elements
#define EPACK_EL   (256 * 64 * 8)              // encoder pipeline pack
#define NTOT       (NPACK + EPACK_EL)          // 377856 (~756 KB)

// workspace byte offsets (after the weight pack)
#define WS_HOFF (768 * 1024)                   // h: 4*2048*64 fp16 = 1 MB
#define WS_COFF (WS_HOFF + 1024 * 1024)        // c: 4*2048*64 f32 = 2 MB

#define PERM(kk) ((((kk) & 3) << 4) | ((kk) >> 2))   // pi^-1
#define PI(c)    ((((c) & 15) << 2) | ((c) >> 4))    // pi

typedef _Float16 h8    __attribute__((ext_vector_type(8)));
typedef _Float16 hh2   __attribute__((ext_vector_type(2)));
typedef float    f32x4 __attribute__((ext_vector_type(4)));

__device__ __forceinline__ void bar_lgkm() {
  asm volatile("s_waitcnt lgkmcnt(0)\n\ts_barrier" ::: "memory");
}

// lane L <-> lane L^16 exchange (BitMode xor=16, and=0x1F)
__device__ __forceinline__ float swz16(float v) {
  int i = __builtin_bit_cast(int, v);
  i = __builtin_amdgcn_ds_swizzle(i, 0x401F);
  return __builtin_bit_cast(float, i);
}

// ---------------------------------------------------------------------------
// Weight pack (identical to rounds 5-13).
// ---------------------------------------------------------------------------
__global__ void prep_weights(const float* __restrict__ eWih0,
                             const float* __restrict__ eWih,
                             const float* __restrict__ eWhh,
                             const float* __restrict__ dWih0,
                             const float* __restrict__ dWih,
                             const float* __restrict__ dWhh,
                             const float* __restrict__ linW,
                             _Float16* __restrict__ wq) {
  int idx = blockIdx.x * blockDim.x + threadIdx.x;
  if (idx >= NTOT) return;

  if (idx >= NPACK) {                      // ---- encoder pipeline pack ----
    int p    = idx - NPACK;
    int j    = p & 7;
    int lane = (p >> 3) & 63;
    int fe   = p >> 9;
    int kt   = fe & 3, nt = (fe >> 2) & 15, l = fe >> 6;
    int g    = nt * 16 + (lane & 15);
    int koff = ((lane >> 4) << 3) + j;
    float v = 0.0f;
    if (l == 0) {
      if (kt == 0)      v = (koff < NIN) ? eWih0[g * NIN + koff] : 0.0f;
      else if (kt == 1) v = 0.0f;
      else { int kk = (kt - 2) * 32 + koff; v = eWhh[g * H + PERM(kk)]; }
    } else {
      if (kt < 2) { int kk = kt * 32 + koff;
                    v = eWih[((l - 1) * 256 + g) * H + PERM(kk)]; }
      else        { int kk = (kt - 2) * 32 + koff;
                    v = eWhh[(l * 256 + g) * H + PERM(kk)]; }
    }
    wq[idx] = (_Float16)v;
    return;
  }

  if (idx >= PACK_H8 * 8) {                // ---- linW A-layout frags ----
    int p    = idx - PACK_H8 * 8;
    int j    = p & 7;
    int lane = (p >> 3) & 63;
    int fr   = p >> 9;
    int m    = lane & 15;
    int k    = fr * 32 + ((lane >> 4) << 3) + j;
    wq[idx] = (_Float16)((m < NIN) ? linW[m * H + k] : 0.0f);
    return;
  }

  // ---- col-sliced pack (decoder uses dec half) ----
  const int j    = idx & 7;
  const int lane = (idx >> 3) & 63;
  const int wv   = (idx >> 9) & 3;
  const int fh   = idx >> 11;
  const int f    = fh % FRAGS_HALF;
  const int half = fh / FRAGS_HALF;
  const float* Wi0 = half ? dWih0 : eWih0;
  const float* Wi  = half ? dWih  : eWih;
  const float* Wh  = half ? dWhh  : eWhh;
  int l, q, kt;
  if (f < 12) { l = 0; q = f / 3; kt = f % 3; }
  else        { int ff = f - 12; l = 1 + ff / 16; ff %= 16; q = ff / 4; kt = ff % 4; }
  const int g    = q * 64 + wv * 16 + (lane & 15);
  const int k_in = ((lane >> 4) << 3) + j;
  float v;
  if (l == 0) {
    if (kt == 0) v = (k_in < NIN) ? Wi0[g * NIN + k_in] : 0.0f;
    else         v = Wh[g * H + (kt - 1) * 32 + k_in];
  } else {
    if (kt < 2) v = Wi[((l - 1) * 256 + g) * H + kt * 32 + k_in];
    else        v = Wh[(l * 256 + g) * H + (kt - 2) * 32 + k_in];
  }
  wq[idx] = (_Float16)v;
}

// ---------------------------------------------------------------------------
__device__ __forceinline__ float rcpf(float x) { return __builtin_amdgcn_rcpf(x); }
__device__ __forceinline__ f32x4 mf(h8 a, h8 b, f32x4 c) {
  return __builtin_amdgcn_mfma_f32_16x16x32_f16(a, b, c, 0, 0, 0);
}
#define SPLAT(v) ((f32x4){(v), (v), (v), (v)})

// merged-rcp LSTM cell: 5 exp + 3 rcp (+2 clamps); absmax-validated R6-R13.
__device__ __forceinline__ float ew_one(float gi, float gf, float gg, float go,
                                        float& c) {
  gg = fminf(fmaxf(gg, -20.0f), 20.0f);
  float eni = __expf(-gi);
  float e2g = __expf(2.0f * gg);
  float enf = __expf(-gf);
  float eno = __expf(-go);
  c = c * rcpf(1.0f + enf) + (e2g - 1.0f) * rcpf((1.0f + eni) * (e2g + 1.0f));
  float cc = fminf(fmaxf(c, -20.0f), 20.0f);
  float e2c = __expf(2.0f * cc);
  return (e2c - 1.0f) * rcpf((1.0f + eno) * (e2c + 1.0f));
}

__device__ __forceinline__ void cell_ew(f32x4 g0, f32x4 g1, f32x4 g2, f32x4 g3,
                                        f32x4& c, _Float16* outbuf,
                                        int quad, int r16, int sl) {
  #pragma unroll
  for (int r = 0; r < 4; r++) {
    float cv = c[r];
    float hv = ew_one(g0[r], g1[r], g2[r], g3[r], cv);
    c[r] = cv;
    outbuf[(quad * 4 + r) * HPAD + sl * 16 + r16] = (_Float16)hv;
  }
}

// compact role-split helpers (FMA order identical to R10 fireH/precH/fire0/prec0)
__device__ __forceinline__ void precc(const h8 (&w)[8], h8 ar0, h8 ar1,
                                      f32x4 b, f32x4 (&ac)[4]) {
  #pragma unroll
  for (int q = 0; q < 4; q++)
    ac[q] = mf(ar1, w[q * 2 + 1], mf(ar0, w[q * 2], SPLAT(b[q])));
}
__device__ __forceinline__ void fireHc(const h8 (&w)[8], h8 ai0, h8 ai1,
                                       const f32x4 (&ac)[4], f32x4& c,
                                       _Float16* outbuf, int quad, int r16, int sl) {
  f32x4 g0 = mf(ai1, w[1], mf(ai0, w[0], ac[0]));
  f32x4 g1 = mf(ai1, w[3], mf(ai0, w[2], ac[1]));
  f32x4 g2 = mf(ai1, w[5], mf(ai0, w[4], ac[2]));
  f32x4 g3 = mf(ai1, w[7], mf(ai0, w[6], ac[3]));
  cell_ew(g0, g1, g2, g3, c, outbuf, quad, r16, sl);
}
__device__ __forceinline__ void fire0c(const h8 (&w)[4], h8 ax,
                                       const f32x4 (&ac)[4], f32x4& c,
                                       _Float16* outbuf, int quad, int r16, int sl) {
  f32x4 g0 = mf(ax, w[0], ac[0]);
  f32x4 g1 = mf(ax, w[1], ac[1]);
  f32x4 g2 = mf(ax, w[2], ac[2]);
  f32x4 g3 = mf(ax, w[3], ac[3]);
  cell_ew(g0, g1, g2, g3, c, outbuf, quad, r16, sl);
}
__device__ __forceinline__ void readA(const _Float16* buf, int r16, int quad,
                                      h8& a0, h8& a1) {
  a0 = *(const h8*)(buf + r16 * HPAD + quad * 8);
  a1 = *(const h8*)(buf + r16 * HPAD + 32 + quad * 8);
}

// ===========================================================================
// ENCODER kernel: 128 blocks x 512 threads, BB=16.  (R10 verbatim.)
// ===========================================================================
__global__ void __launch_bounds__(512, 2)
lstm_enc(const float* __restrict__ X,
         const float* __restrict__ encb,
         const h8* __restrict__ WQ,
         _Float16* __restrict__ hG,
         float* __restrict__ cG) {
  __shared__ _Float16 Hb[NL][2][16][HPAD];   // 18432 B
  __shared__ _Float16 Xb[2][16][HPAD];       //  4608 B

  const int tid  = threadIdx.x;
  const int wv   = tid >> 6;        // 0..7
  const int lane = tid & 63;
  const int quad = lane >> 4;
  const int r16  = lane & 15;
  const int grp  = wv >> 2;         // col-half
  const int lw   = wv & 3;          // layer
  const int bbase = blockIdx.x * 16;

  {
    float* p = (float*)&Hb[0][0][0][0];
    for (int i = tid; i < 4608; i += 512) p[i] = 0.0f;
    float* px = (float*)&Xb[0][0][0];
    for (int i = tid; i < 1152; i += 512) px[i] = 0.0f;
  }
  if (tid < 16 * NIN) {
    int m = tid / NIN, ii = tid - m * NIN;
    Xb[0][m][ii] = (_Float16)X[((size_t)0 * BATCH + bbase + m) * NIN + ii];
  }

  // weights: 8 n-tiles {q*4 + 2*grp + cc}, 4 k-tiles each
  h8 we[8][4];
  #pragma unroll
  for (int q = 0; q < 4; q++)
    #pragma unroll
    for (int cc = 0; cc < 2; cc++)
      #pragma unroll
      for (int kt = 0; kt < 4; kt++)
        we[q * 2 + cc][kt] =
            WQ[(PACK_H8 + PROJ_H8) +
               ((lw * 64 + (q * 4 + 2 * grp + cc) * 4 + kt) * 64 + lane)];
  float ben[8];
  #pragma unroll
  for (int q = 0; q < 4; q++)
    #pragma unroll
    for (int cc = 0; cc < 2; cc++)
      ben[q * 2 + cc] = encb[lw * 256 + q * 64 + (2 * grp + cc) * 16 + r16];

  f32x4 ce[2];
  ce[0] = SPLAT(0.f); ce[1] = SPLAT(0.f);

  // 2-deep x prefetch: wave (lw=0, grp=0), lanes 0..47, 2 floats each
  const bool pfLane = (wv == 0) && (lane < 48);
  const int  pe0 = lane * 2, pe1 = pe0 + 1;
  const int  pm0 = pe0 / NIN, pc0 = pe0 % NIN;
  const int  pm1 = pe1 / NIN, pc1 = pe1 % NIN;
  float pf0 = 0.f, pf1 = 0.f;
  if (pfLane) {
    const float* xs = X + ((size_t)1 * BATCH + bbase) * NIN;
    pf0 = xs[pe0]; pf1 = xs[pe1];
  }

  __syncthreads();

  #pragma unroll 1
  for (int i = 0; i < S_LEN + NL - 1; i++) {     // 123 intervals
    const int p = i & 1;
    const bool active = (i >= lw) && (i - lw < S_LEN);
    if (active) {
      const _Float16* inb = (lw == 0) ? &Xb[p][0][0] : &Hb[lw - 1][p ^ 1][0][0];
      const _Float16* rcb = &Hb[lw][p ^ 1][0][0];
      h8 ai0 = *(const h8*)(inb + r16 * HPAD + quad * 8);
      h8 ai1 = {};
      if (lw) ai1 = *(const h8*)(inb + r16 * HPAD + 32 + quad * 8);
      h8 ar0 = *(const h8*)(rcb + r16 * HPAD + quad * 8);
      h8 ar1 = *(const h8*)(rcb + r16 * HPAD + 32 + quad * 8);

      float nf0 = 0.f, nf1 = 0.f;
      if (pfLane && (i + 2 < S_LEN)) {
        const float* xs = X + ((size_t)(i + 2) * BATCH + bbase) * NIN;
        nf0 = xs[pe0]; nf1 = xs[pe1];
      }

      f32x4 a[8];
      #pragma unroll
      for (int j = 0; j < 8; j++) {
        f32x4 t = SPLAT(ben[j]);
        t = mf(ai0, we[j][0], t);
        if (lw) t = mf(ai1, we[j][1], t);
        t = mf(ar0, we[j][2], t);
        t = mf(ar1, we[j][3], t);
        a[j] = t;
      }

      _Float16* wb = &Hb[lw][p][0][0];
      #pragma unroll
      for (int r = 0; r < 4; r++) {
        hh2 hv;
        #pragma unroll
        for (int cc = 0; cc < 2; cc++) {
          float cv = ce[cc][r];
          hv[cc] = (_Float16)ew_one(a[cc][r], a[2 + cc][r],
                                    a[4 + cc][r], a[6 + cc][r], cv);
          ce[cc][r] = cv;
        }
        // permuted layout: col c = ct*16+r16 lands at 4*r16+ct; ct = 2*grp+cc
        *(hh2*)(wb + (quad * 4 + r) * HPAD + 4 * r16 + 2 * grp) = hv;
      }

      if (pfLane && (i + 1 < S_LEN)) {
        Xb[p ^ 1][pm0][pc0] = (_Float16)pf0;
        Xb[p ^ 1][pm1][pc1] = (_Float16)pf1;
      }
      pf0 = nf0; pf1 = nf1;
    }
    bar_lgkm();
  }

  // ---- store c to global (per-lane direct) ----
  #pragma unroll
  for (int cc = 0; cc < 2; cc++)
    #pragma unroll
    for (int r = 0; r < 4; r++)
      cG[((size_t)lw * BATCH + bbase + quad * 4 + r) * H +
         (2 * grp + cc) * 16 + r16] = ce[cc][r];

  // ---- store final h (unpermute via PI) to global ----
  #pragma unroll
  for (int u = 0; u < 8; u++) {
    int i2 = tid + u * 512;
    int c = i2 & 63, m = (i2 >> 6) & 15, l = (i2 >> 10) & 3;
    hG[((size_t)l * BATCH + bbase + m) * H + c] =
        Hb[l][(l + 1) & 1][m][PI(c)];
  }
}

// ===========================================================================
// DECODER kernel: 128 blocks x 512 threads, 8 waves = 4 col-slices x {F,P}.
// 2 waves/SIMD (1F+1P per SIMD). AC handoff lane-contiguous (R13-validated).
// R14: F-waves at s_setprio(1); xa build via 2x ds_swizzle xor-16.
// FMA accumulation order bit-identical to R10.
// ===========================================================================
__global__ void __launch_bounds__(512, 2)
lstm_dec(const float* __restrict__ X,
         const float* __restrict__ decb,
         const float* __restrict__ linb,
         const h8* __restrict__ WQ,
         const _Float16* __restrict__ hG,
         const float* __restrict__ cG,
         float* __restrict__ out) {
  __shared__ _Float16 Hb[NL][2][16][HPAD];   // 18432 B
  __shared__ f32x4 ACs[NL][4][4][64];        // 65536 B, [l][sl][j][lane]

  const int tid   = threadIdx.x;
  const int wv    = tid >> 6;        // 0..7
  const int sl    = wv & 3;          // col-slice
  const int roleP = wv >> 2;         // 0 = fire wave, 1 = prec wave
  const int lane  = tid & 63;
  const int quad  = lane >> 4;
  const int r16   = lane & 15;
  const int bbase = blockIdx.x * 16;

  // load encoder-final h into Hb[l][1] (all 512 threads)
  #pragma unroll
  for (int u = 0; u < 8; u++) {
    int i2 = tid + u * 512;
    int l = i2 >> 10, m = (i2 >> 6) & 15, c = i2 & 63;
    Hb[l][1][m][c] = hG[((size_t)l * BATCH + bbase + m) * H + c];
  }
  __syncthreads();   // h-load visible

  if (roleP) {
    // ================= P wave: recurrent precompute =================
    h8 wp0[8], wpH[3][8];
    #pragma unroll
    for (int e = 0; e < 8; e++) {
      int q = e >> 1, k = e & 1;
      wp0[e] = WQ[((FRAGS_HALF + q * 3 + 1 + k) * 4 + sl) * 64 + lane];
    }
    #pragma unroll
    for (int l = 0; l < 3; l++)
      #pragma unroll
      for (int e = 0; e < 8; e++) {
        int q = e >> 1, k = e & 1;
        wpH[l][e] = WQ[((FRAGS_HALF + 12 + l * 16 + q * 4 + 2 + k) * 4 + sl) * 64 + lane];
      }
    f32x4 b0, b1, b2, b3;
    #pragma unroll
    for (int q = 0; q < 4; q++) {
      b0[q] = decb[0 * 256 + q * 64 + sl * 16 + r16];
      b1[q] = decb[1 * 256 + q * 64 + sl * 16 + r16];
      b2[q] = decb[2 * 256 + q * 64 + sl * 16 + r16];
      b3[q] = decb[3 * 256 + q * 64 + sl * 16 + r16];
    }

    // seed: prec layers 0,1,2 from encoder-final h
    {
      h8 s0, s1;
      f32x4 a[4];
      readA(&Hb[0][1][0][0], r16, quad, s0, s1);
      precc(wp0, s0, s1, b0, a);
      #pragma unroll
      for (int j = 0; j < 4; j++) ACs[0][sl][j][lane] = a[j];
      readA(&Hb[1][1][0][0], r16, quad, s0, s1);
      precc(wpH[0], s0, s1, b1, a);
      #pragma unroll
      for (int j = 0; j < 4; j++) ACs[1][sl][j][lane] = a[j];
      readA(&Hb[2][1][0][0], r16, quad, s0, s1);
      precc(wpH[1], s0, s1, b2, a);
      #pragma unroll
      for (int j = 0; j < 4; j++) ACs[2][sl][j][lane] = a[j];
    }
    bar_lgkm();   // matches F's pre-loop bar

    #pragma unroll 1
    for (int t = 0; t < TLEN; t++) {
      const int cur = t & 1, prv = cur ^ 1;
      { // ---- A: prec layer3 from h3[prv] ----
        h8 a0, a1; readA(&Hb[3][prv][0][0], r16, quad, a0, a1);
        f32x4 a[4]; precc(wpH[2], a0, a1, b3, a);
        #pragma unroll
        for (int j = 0; j < 4; j++) ACs[3][sl][j][lane] = a[j];
        bar_lgkm();
      }
      { // ---- B: prec layer0 from h0[cur] ----
        h8 a0, a1; readA(&Hb[0][cur][0][0], r16, quad, a0, a1);
        f32x4 a[4]; precc(wp0, a0, a1, b0, a);
        #pragma unroll
        for (int j = 0; j < 4; j++) ACs[0][sl][j][lane] = a[j];
        bar_lgkm();
      }
      { // ---- C: prec layer1 from h1[cur] ----
        h8 a0, a1; readA(&Hb[1][cur][0][0], r16, quad, a0, a1);
        f32x4 a[4]; precc(wpH[0], a0, a1, b1, a);
        #pragma unroll
        for (int j = 0; j < 4; j++) ACs[1][sl][j][lane] = a[j];
        bar_lgkm();
      }
      { // ---- D: prec layer2 from h2[cur] ----
        h8 a0, a1; readA(&Hb[2][cur][0][0], r16, quad, a0, a1);
        f32x4 a[4]; precc(wpH[1], a0, a1, b2, a);
        #pragma unroll
        for (int j = 0; j < 4; j++) ACs[2][sl][j][lane] = a[j];
        bar_lgkm();
      }
    }
  } else {
    // ================= F wave: fire + ew + proj (setprio 1) =================
    h8 wf0[4], wfH[3][8];
    #pragma unroll
    for (int q = 0; q < 4; q++)
      wf0[q] = WQ[((FRAGS_HALF + q * 3) * 4 + sl) * 64 + lane];
    #pragma unroll
    for (int l = 0; l < 3; l++)
      #pragma unroll
      for (int e = 0; e < 8; e++) {
        int q = e >> 1, k = e & 1;
        wfH[l][e] = WQ[((FRAGS_HALF + 12 + l * 16 + q * 4 + k) * 4 + sl) * 64 + lane];
      }

    // c slices
    f32x4 cs0, cs1, cs2, cs3;
    #pragma unroll
    for (int r = 0; r < 4; r++) {
      cs0[r] = cG[((size_t)0 * BATCH + bbase + quad * 4 + r) * H + sl * 16 + r16];
      cs1[r] = cG[((size_t)1 * BATCH + bbase + quad * 4 + r) * H + sl * 16 + r16];
      cs2[r] = cG[((size_t)2 * BATCH + bbase + quad * 4 + r) * H + sl * 16 + r16];
      cs3[r] = cG[((size_t)3 * BATCH + bbase + quad * 4 + r) * H + sl * 16 + r16];
    }

    h8 lwA0 = WQ[PACK_H8 + lane];
    h8 lwA1 = WQ[PACK_H8 + 64 + lane];
    f32x4 lbq;
    #pragma unroll
    for (int r = 0; r < 4; r++)
      lbq[r] = (quad * 4 + r < NIN) ? linb[quad * 4 + r] : 0.0f;

    // x[119] A-frag (k = quad*8+j; only k<6 real)
    h8 xseed = {};
    if (quad == 0) {
      const float* xs = X + ((size_t)(S_LEN - 1) * BATCH + bbase + r16) * NIN;
      #pragma unroll
      for (int j = 0; j < 6; j++) xseed[j] = (_Float16)xs[j];
    }

    bar_lgkm();   // matches P's seed bar

    __builtin_amdgcn_s_setprio(1);   // F gates every barrier; bias issue to it

    #pragma unroll 1
    for (int t = 0; t < TLEN; t++) {
      const int cur = t & 1, prv = cur ^ 1;
      { // ---- A: proj(h3[t-1]) + layer-0 fire ----
        h8 ar0, ar1;
        readA(&Hb[3][prv][0][0], r16, quad, ar0, ar1);
        h8 ax;
        if (t == 0) {
          ax = xseed;
        } else {
          f32x4 ap = lbq;
          ap = mf(lwA0, ar0, ap);     // A = linW (m=feature), B = h3 (n=batch)
          ap = mf(lwA1, ar1, ap);
          if (sl == 0) {
            #pragma unroll
            for (int r = 0; r < 4; r++) {
              const int fm = quad * 4 + r;
              if (fm < NIN)
                out[((size_t)(t - 1) * BATCH + bbase + r16) * NIN + fm] = ap[r];
            }
          }
          // xa consumers are quad==0 lanes: shfl(ap[r], r16) is identity there;
          // feats 4,5 come from quad1 = lane^16 -> ds_swizzle xor-16.
          float x4 = swz16(ap[0]);
          float x5 = swz16(ap[1]);
          h8 xa = {};
          xa[0] = (_Float16)ap[0]; xa[1] = (_Float16)ap[1];
          xa[2] = (_Float16)ap[2]; xa[3] = (_Float16)ap[3];
          xa[4] = (_Float16)x4;    xa[5] = (_Float16)x5;
          h8 zz = {};
          ax = (quad == 0) ? xa : zz;
        }
        f32x4 ac[4];
        #pragma unroll
        for (int j = 0; j < 4; j++) ac[j] = ACs[0][sl][j][lane];
        fire0c(wf0, ax, ac, cs0, &Hb[0][cur][0][0], quad, r16, sl);
        bar_lgkm();
      }
      { // ---- B: fire layer1 ----
        h8 ai0, ai1;
        readA(&Hb[0][cur][0][0], r16, quad, ai0, ai1);
        f32x4 ac[4];
        #pragma unroll
        for (int j = 0; j < 4; j++) ac[j] = ACs[1][sl][j][lane];
        fireHc(wfH[0], ai0, ai1, ac, cs1, &Hb[1][cur][0][0], quad, r16, sl);
        bar_lgkm();
      }
      { // ---- C: fire layer2 ----
        h8 ai0, ai1;
        readA(&Hb[1][cur][0][0], r16, quad, ai0, ai1);
        f32x4 ac[4];
        #pragma unroll
        for (int j = 0; j < 4; j++) ac[j] = ACs[2][sl][j][lane];
        fireHc(wfH[1], ai0, ai1, ac, cs2, &Hb[2][cur][0][0], quad, r16, sl);
        bar_lgkm();
      }
      { // ---- D: fire layer3 ----
        h8 ai0, ai1;
        readA(&Hb[2][cur][0][0], r16, quad, ai0, ai1);
        f32x4 ac[4];
        #pragma unroll
        for (int j = 0; j < 4; j++) ac[j] = ACs[3][sl][j][lane];
        fireHc(wfH[2], ai0, ai1, ac, cs3, &Hb[3][cur][0][0], quad, r16, sl);
        bar_lgkm();
      }
    }

    __builtin_amdgcn_s_setprio(0);

    // epilogue: out[TLEN-1] from h3 of last step (parity 1)
    if (sl == 0) {
      h8 ar0, ar1;
      readA(&Hb[3][1][0][0], r16, quad, ar0, ar1);
      f32x4 ap = lbq;
      ap = mf(lwA0, ar0, ap);
      ap = mf(lwA1, ar1, ap);
      #pragma unroll
      for (int r = 0; r < 4; r++) {
        const int fm = quad * 4 + r;
        if (fm < NIN)
          out[((size_t)(TLEN - 1) * BATCH + bbase + r16) * NIN + fm] = ap[r];
      }
    }
  }
}

// ---------------------------------------------------------------------------
extern "C" void kernel_launch(void* const* d_in, const int* in_sizes, int n_in,
                              void* d_out, int out_size, void* d_ws, size_t ws_size,
                              hipStream_t stream) {
  const float* X     = (const float*)d_in[0];
  const float* eWih0 = (const float*)d_in[1];
  const float* eWih  = (const float*)d_in[2];
  const float* eWhh  = (const float*)d_in[3];
  const float* eb    = (const float*)d_in[4];
  const float* dWih0 = (const float*)d_in[5];
  const float* dWih  = (const float*)d_in[6];
  const float* dWhh  = (const float*)d_in[7];
  const float* db    = (const float*)d_in[8];
  const float* lW    = (const float*)d_in[9];
  const float* lb    = (const float*)d_in[10];

  _Float16* wq = (_Float16*)d_ws;
  _Float16* hG = (_Float16*)((char*)d_ws + WS_HOFF);
  float*    cG = (float*)((char*)d_ws + WS_COFF);

  prep_weights<<<(NTOT + 255) / 256, 256, 0, stream>>>(
      eWih0, eWih, eWhh, dWih0, dWih, dWhh, lW, wq);

  lstm_enc<<<BATCH / 16, 512, 0, stream>>>(
      X, eb, (const h8*)wq, hG, cG);

  lstm_dec<<<BATCH / 16, 512, 0, stream>>>(
      X, db, lb, (const h8*)wq, hG, cG, (float*)d_out);
}